// Round 8
// baseline (11075.557 us; speedup 1.0000x reference)
//
#include <hip/hip_runtime.h>
#include <hip/hip_bf16.h>
#include <stdint.h>

#define B_   512
#define H_   1024
#define T_   144
#define NG   4096
#define NOUT 17

typedef __bf16 bf16_t;
typedef __bf16 bf16x8 __attribute__((ext_vector_type(8)));
typedef float  f32x4  __attribute__((ext_vector_type(4)));

__device__ __host__ __forceinline__ int npack(int n) {
  int g = n >> 10, j = n & 1023;
  return ((j >> 4) << 6) + (g << 4) + (j & 15);
}
__device__ __forceinline__ float sigf(float x) { return 1.f / (1.f + __expf(-x)); }
__device__ __forceinline__ float tanhf_(float x) { return 1.f - 2.f / (__expf(2.f * x) + 1.f); }

// ---------------- prep kernels (same layouts as r6/r7) ----------------

__global__ void k_pack_wA(const float* __restrict__ Whh0, bf16_t* __restrict__ PB1) {
  int idx = blockIdx.x * 256 + threadIdx.x;     // 4096*128
  int n = idx >> 7, kc = idx & 127;
  const float* s = Whh0 + (size_t)n * H_ + kc * 8;
  bf16x8 v;
#pragma unroll
  for (int e = 0; e < 8; ++e) v[e] = (bf16_t)s[e];
  int np = npack(n), jt = np >> 6, r = np & 63;
  *(bf16x8*)(PB1 + (size_t)jt * 65536 + (kc >> 2) * 2048 + r * 32 + (kc & 3) * 8) = v;
}

__global__ void k_pack_wB(const float* __restrict__ Wih1, const float* __restrict__ Whh1,
                          bf16_t* __restrict__ PB2) {
  int idx = blockIdx.x * 256 + threadIdx.x;     // 4096*256
  int n = idx >> 8, kc = idx & 255;
  int k = kc * 8;
  const float* s = (k < H_) ? (Wih1 + (size_t)n * H_ + k) : (Whh1 + (size_t)n * H_ + (k - H_));
  bf16x8 v;
#pragma unroll
  for (int e = 0; e < 8; ++e) v[e] = (bf16_t)s[e];
  int np = npack(n), jt = np >> 6, r = np & 63;
  *(bf16x8*)(PB2 + (size_t)jt * 131072 + (kc >> 2) * 2048 + r * 32 + (kc & 3) * 8) = v;
}

__global__ void k_G(const float* __restrict__ Wih0, const float* __restrict__ ffW,
                    const float* __restrict__ ffb, float* __restrict__ G) {
  int n = blockIdx.x * 256 + threadIdx.x;       // 4096
  float acc[33];
#pragma unroll
  for (int c = 0; c < 33; ++c) acc[c] = 0.f;
  for (int k = 0; k < 512; ++k) {
    float wv = Wih0[(size_t)n * H_ + 512 + k];
    const float* fr = ffW + (size_t)k * 32;
#pragma unroll
    for (int c = 0; c < 32; ++c) acc[c] += wv * fr[c];
    acc[32] += wv * ffb[k];
  }
  for (int c = 0; c < 33; ++c) G[(size_t)c * NG + n] = acc[c];
}

__global__ void k_CHp(const float* __restrict__ cond, const float* __restrict__ G,
                      const float* __restrict__ bih0, const float* __restrict__ bhh0,
                      float* __restrict__ CHp) {
  int idx = blockIdx.x * 256 + threadIdx.x;     // 512*4096
  int b = idx >> 12, n = idx & 4095;
  float acc = bih0[n] + bhh0[n] + G[(size_t)32 * NG + n];
  const float* cb = cond + (size_t)b * 32;
#pragma unroll
  for (int c = 0; c < 32; ++c) acc += cb[c] * G[(size_t)c * NG + n];
  CHp[(size_t)b * NG + npack(n)] = acc;
}

__global__ void k_E16(const float* __restrict__ emb, const float* __restrict__ Wih0,
                      float* __restrict__ E16p) {
  int idx = blockIdx.x * 256 + threadIdx.x;     // 16*4096
  int a = idx & 15, n = idx >> 4;
  const float* er = emb + (size_t)a * 511;
  const float* wr = Wih0 + (size_t)n * H_;
  float acc = 0.f;
  for (int k = 0; k < 511; ++k) acc += er[k] * wr[k];
  E16p[(size_t)a * NG + npack(n)] = acc;
}

__global__ void k_misc(const float* __restrict__ Wih0, const float* __restrict__ bih,
                       const float* __restrict__ bhh, const float* __restrict__ fcW,
                       bf16_t* __restrict__ fcWp, float* __restrict__ biasBp,
                       float* __restrict__ wcolp) {
  int idx = blockIdx.x * 256 + threadIdx.x;     // 17408
  if (idx < NG) {
    int np = npack(idx);
    biasBp[np] = bih[NG + idx] + bhh[NG + idx];
    wcolp[np]  = Wih0[(size_t)idx * H_ + 511];
  }
  if (idx < 17 * H_) fcWp[idx] = (bf16_t)fcW[idx];
}

__global__ void k_init(const float* __restrict__ h0,
                       bf16_t* __restrict__ pah0i, bf16_t* __restrict__ pah1a) {
  int idx = blockIdx.x * 256 + threadIdx.x;     // 512*128
  int b = idx >> 7, kc = idx & 127;
  const float* s0 = h0 + (size_t)b * H_ + kc * 8;
  const float* s1 = s0 + (size_t)B_ * H_;
  bf16x8 v0, v1;
#pragma unroll
  for (int e = 0; e < 8; ++e) { v0[e] = (bf16_t)s0[e]; v1[e] = (bf16_t)s1[e]; }
  size_t po = (size_t)(kc >> 2) * 16384 + b * 32 + (kc & 3) * 8;
  *(bf16x8*)(pah0i + po) = v0;
  *(bf16x8*)(pah1a + po) = v1;
}

// ---------------- output finalization ----------------

__global__ void k_out(const float* __restrict__ preds, const float* __restrict__ fcb,
                      float* __restrict__ out) {
  int idx = blockIdx.x * 256 + threadIdx.x;     // T*B
  if (idx >= T_ * B_) return;
  int t = idx % T_, b = idx / T_;
  const float* pr = preds + ((size_t)t * B_ + b) * NOUT;
  float v[NOUT];
#pragma unroll
  for (int o = 0; o < NOUT; ++o) v[o] = pr[o] + fcb[o];
  float m = v[0];
#pragma unroll
  for (int o = 1; o < 16; ++o) m = fmaxf(m, v[o]);
  float s = 0.f;
#pragma unroll
  for (int o = 0; o < 16; ++o) s += expf(v[o] - m);
  float lse = m + logf(s);
  float* dst = out + ((size_t)b * T_ + t) * NOUT;
#pragma unroll
  for (int o = 0; o < 16; ++o) dst[o] = v[o] - lse;
  float x = v[16];
  dst[16] = (x > 0.f) ? -log1pf(expf(-x)) : (x - log1pf(expf(x)));
}

// ---------------- main persistent kernel ----------------

struct Params {
  const int* acts; const float* durs;
  const bf16_t* PB1; const bf16_t* PB2;
  const float* CHp; const float* E16p; const float* wcolp; const float* biasBp;
  const bf16_t* fcW;
  const float* c0in;
  const bf16_t* pah0i;
  bf16_t* pah0a; bf16_t* pah0b; bf16_t* pah1a; bf16_t* pah1b;
  unsigned* slots; float* preds;
};

// flag-slot grid barrier, 512 WGs: store-release own slot, poll 2 slots/thread
__device__ __forceinline__ void gbar(unsigned* slots, unsigned phase, int tid, int wg) {
  __syncthreads();
  if (tid == 0) {
    __builtin_amdgcn_fence(__ATOMIC_RELEASE, "agent");
    __hip_atomic_store(slots + (size_t)wg * 16, phase, __ATOMIC_RELAXED, __HIP_MEMORY_SCOPE_AGENT);
  }
  {
    const unsigned* a0 = slots + (size_t)tid * 16;
    const unsigned* a1 = slots + (size_t)(tid + 256) * 16;
    while (__hip_atomic_load(a0, __ATOMIC_RELAXED, __HIP_MEMORY_SCOPE_SYSTEM) < phase)
      __builtin_amdgcn_s_sleep(1);
    while (__hip_atomic_load(a1, __ATOMIC_RELAXED, __HIP_MEMORY_SCOPE_SYSTEM) < phase)
      __builtin_amdgcn_s_sleep(1);
  }
  __syncthreads();
}

// merged-block slot: h0-frag (a), h1-frag (e), W0 (b), W1ih (c), W1hh (d)
struct Slot { bf16x8 a0, e0, b0, b1, b2, b3, c0, c1, c2, c3, d0, d1, d2, d3; };

__device__ __forceinline__ void ldA1(bf16x8& r0, const char* p) {
  asm volatile("global_load_dwordx4 %0, %1, off sc0 sc1" : "=&v"(r0) : "v"(p));
}
__device__ __forceinline__ void ldA1pl(bf16x8& r0, const char* p) {
  asm volatile("global_load_dwordx4 %0, %1, off" : "=&v"(r0) : "v"(p));
}
__device__ __forceinline__ void ldB4(bf16x8& r0, bf16x8& r1, bf16x8& r2, bf16x8& r3,
                                     const char* p) {
  asm volatile("global_load_dwordx4 %0, %4, off\n\t"
               "global_load_dwordx4 %1, %4, off offset:1024\n\t"
               "global_load_dwordx4 %2, %4, off offset:2048\n\t"
               "global_load_dwordx4 %3, %4, off offset:3072"
               : "=&v"(r0), "=&v"(r1), "=&v"(r2), "=&v"(r3) : "v"(p));
}

#define VMW(N) { asm volatile("s_waitcnt vmcnt(" #N ")" ::: "memory"); \
                 __builtin_amdgcn_sched_barrier(0); }

#define MFM(ACC, AV, BV) ACC = __builtin_amdgcn_mfma_f32_16x16x32_bf16(AV, BV, ACC, 0, 0, 0)

__device__ __forceinline__ void compS(f32x4 (&A0)[4], f32x4 (&A1)[4], const Slot& S) {
  MFM(A0[0], S.a0, S.b0); MFM(A0[1], S.a0, S.b1);
  MFM(A0[2], S.a0, S.b2); MFM(A0[3], S.a0, S.b3);
  MFM(A1[0], S.a0, S.c0); MFM(A1[1], S.a0, S.c1);
  MFM(A1[2], S.a0, S.c2); MFM(A1[3], S.a0, S.c3);
  MFM(A1[0], S.e0, S.d0); MFM(A1[1], S.e0, S.d1);
  MFM(A1[2], S.e0, S.d2); MFM(A1[3], S.e0, S.d3);
}

__device__ __forceinline__ void compP(f32x4 (&A0)[4], const Slot& S) {
  MFM(A0[0], S.a0, S.b0); MFM(A0[1], S.a0, S.b1);
  MFM(A0[2], S.a0, S.b2); MFM(A0[3], S.a0, S.b3);
}

__global__ __launch_bounds__(256, 2) void lstm_main(Params p) {
  const int tid = threadIdx.x;
  const int w = tid >> 6, l = tid & 63;
  const int wg = blockIdx.x;                 // 512 WGs
  const int mt2 = (wg >> 3) & 7;             // 8 M-tiles of 64 rows
  const int jt = ((wg >> 6) << 3) | (wg & 7);// 64 jt; per XCD: 8 jt x 8 mt
  const int jj = l & 15, rq = l >> 4;
  const int jcol = jt * 16 + jj;
  const int npb = jt * 64;
  const int a_off = (mt2 * 64 + w * 16 + jj) * 64 + rq * 16;  // byte off in kk-block
  const int b_off = jj * 64 + rq * 16;
  const char* Bw0 = (const char*)p.PB1 + (size_t)jt * 131072;
  const char* Bw1 = (const char*)p.PB2 + (size_t)jt * 262144;
  const int he_off = (jcol >> 5) * 16384 + (jcol & 31);

  // fc-head rows kept in bf16: lane jj owns output o=jj
  bf16x8 fcw_a, fcw_b, fw16_a, fw16_b;
  {
    const char* fwp = (const char*)p.fcW;
    fcw_a  = *(const bf16x8*)(fwp + jj * 2048 + jt * 32);
    fcw_b  = *(const bf16x8*)(fwp + jj * 2048 + jt * 32 + 16);
    fw16_a = *(const bf16x8*)(fwp + 16 * 2048 + jt * 32);
    fw16_b = *(const bf16x8*)(fwp + 16 * 2048 + jt * 32 + 16);
  }

  // hoisted t-invariant per-thread state: c-state, biases, AND CHp (16 regs —
  // r7 de-hoisted this to L2 and the added pressure thrashed weights to HBM)
  float chv[4][4], cv0[4], cv1[4], bzv[4], wcv[4];
#pragma unroll
  for (int qq = 0; qq < 4; ++qq) {
    int b = mt2 * 64 + w * 16 + rq * 4 + qq;
    cv0[qq] = p.c0in[(size_t)b * H_ + jcol];
    cv1[qq] = p.c0in[(size_t)B_ * H_ + (size_t)b * H_ + jcol];
#pragma unroll
    for (int g = 0; g < 4; ++g)
      chv[qq][g] = p.CHp[(size_t)b * NG + npb + g * 16 + jj];
  }
#pragma unroll
  for (int g = 0; g < 4; ++g) {
    bzv[g] = p.biasBp[npb + g * 16 + jj];
    wcv[g] = p.wcolp[npb + g * 16 + jj];
  }

  Slot S0, S1, S2;

  // ======== prologue: h0^(0) = cell0(x_0, h0_init) ========
  {
    f32x4 acc0[4];
#pragma unroll
    for (int g = 0; g < 4; ++g) acc0[g] = (f32x4){0.f, 0.f, 0.f, 0.f};

    const char* Ai = (const char*)p.pah0i;
    auto Pp = [&](int kk, Slot& S) {
      ldA1pl(S.a0, Ai + (size_t)kk * 32768 + a_off);
      ldB4(S.b0, S.b1, S.b2, S.b3, Bw0 + (size_t)kk * 4096 + b_off);
    };
    Pp(0, S0); Pp(1, S1);
#pragma unroll 1
    for (int o = 0; o < 10; ++o) {
      const int k = o * 3;
      Pp(k + 2, S2); VMW(10); compP(acc0, S0);
      Pp(k + 3, S0); VMW(10); compP(acc0, S1);
      Pp(k + 4, S1); VMW(10); compP(acc0, S2);
    }
    VMW(5);  compP(acc0, S0);
    VMW(0);  compP(acc0, S1);

    bf16_t* H0n = p.pah0a;
#pragma unroll
    for (int qq = 0; qq < 4; ++qq) {
      int b = mt2 * 64 + w * 16 + rq * 4 + qq;
      float pre[4];
#pragma unroll
      for (int g = 0; g < 4; ++g)
        pre[g] = acc0[g][qq] + chv[qq][g] + p.E16p[npb + g * 16 + jj];
      float cn = sigf(pre[1]) * cv0[qq] + sigf(pre[0]) * tanhf_(pre[2]);
      float hn = sigf(pre[3]) * tanhf_(cn);
      cv0[qq] = cn;
      H0n[(size_t)he_off + b * 32] = (bf16_t)hn;
    }
    gbar(p.slots, 1u, tid, wg);
  }

  // ======== main: superstep s computes h1^(s) AND h0^(s+1), one barrier ========
#pragma unroll 1
  for (int s = 0; s < T_; ++s) {
    const char* Ah0 = (const char*)((s & 1) ? p.pah0b : p.pah0a);
    bf16_t*     H0n = (s & 1) ? p.pah0a : p.pah0b;
    const char* Ah1 = (const char*)((s & 1) ? p.pah1b : p.pah1a);
    bf16_t*     H1n = (s & 1) ? p.pah1a : p.pah1b;

    f32x4 acc0[4], acc1[4];
#pragma unroll
    for (int g = 0; g < 4; ++g) {
      acc0[g] = (f32x4){0.f, 0.f, 0.f, 0.f};
      acc1[g] = (f32x4){0.f, 0.f, 0.f, 0.f};
    }

    auto Pm = [&](int kk, Slot& S) {
      ldA1(S.a0, Ah0 + (size_t)kk * 32768 + a_off);
      ldA1(S.e0, Ah1 + (size_t)kk * 32768 + a_off);
      ldB4(S.b0, S.b1, S.b2, S.b3, Bw0 + (size_t)kk * 4096 + b_off);
      ldB4(S.c0, S.c1, S.c2, S.c3, Bw1 + (size_t)kk * 4096 + b_off);
      ldB4(S.d0, S.d1, S.d2, S.d3, Bw1 + (size_t)(32 + kk) * 4096 + b_off);
    };
    Pm(0, S0); Pm(1, S1);
#pragma unroll 1
    for (int o = 0; o < 10; ++o) {
      const int k = o * 3;
      Pm(k + 2, S2); VMW(28); compS(acc0, acc1, S0);
      Pm(k + 3, S0); VMW(28); compS(acc0, acc1, S1);
      Pm(k + 4, S1); VMW(28); compS(acc0, acc1, S2);
    }
    VMW(14); compS(acc0, acc1, S0);
    VMW(0);  compS(acc0, acc1, S1);

    // epilogue: cell1 -> h1^(s) + fc head;  cell0 -> h0^(s+1)
#pragma unroll
    for (int qq = 0; qq < 4; ++qq) {
      int b = mt2 * 64 + w * 16 + rq * 4 + qq;
      // ---- layer 1 cell ----
      float pre1[4];
#pragma unroll
      for (int g = 0; g < 4; ++g) pre1[g] = acc1[g][qq] + bzv[g];
      float cn1 = sigf(pre1[1]) * cv1[qq] + sigf(pre1[0]) * tanhf_(pre1[2]);
      float hn1 = sigf(pre1[3]) * tanhf_(cn1);
      cv1[qq] = cn1;
      H1n[(size_t)he_off + b * 32] = (bf16_t)hn1;
      // fc-head partials over this WG's 16 columns
      float accO = 0.f, acc16 = 0.f;
#pragma unroll
      for (int sc = 0; sc < 8; ++sc) {
        float hs = __shfl(hn1, (l & 48) | sc, 64);
        accO  += hs * (float)fcw_a[sc];
        acc16 += hs * (float)fw16_a[sc];
      }
#pragma unroll
      for (int sc = 0; sc < 8; ++sc) {
        float hs = __shfl(hn1, (l & 48) | (8 + sc), 64);
        accO  += hs * (float)fcw_b[sc];
        acc16 += hs * (float)fw16_b[sc];
      }
      float* pb = p.preds + ((size_t)s * B_ + b) * NOUT;
      atomicAdd(pb + jj, accO);
      if (jj == 15) atomicAdd(pb + 16, acc16);
      // ---- layer 0 cell (next step's h0) ----
      int act = p.acts[(size_t)b * T_ + s];
      float dur = p.durs[(size_t)b * T_ + s];
      float pre0[4];
#pragma unroll
      for (int g = 0; g < 4; ++g)
        pre0[g] = acc0[g][qq] + chv[qq][g]
                + p.E16p[(size_t)act * NG + npb + g * 16 + jj] + dur * wcv[g];
      float cn0 = sigf(pre0[1]) * cv0[qq] + sigf(pre0[0]) * tanhf_(pre0[2]);
      float hn0 = sigf(pre0[3]) * tanhf_(cn0);
      cv0[qq] = cn0;
      H0n[(size_t)he_off + b * 32] = (bf16_t)hn0;
    }
    gbar(p.slots, (unsigned)(s + 2), tid, wg);
  }
}

// ---------------- launch ----------------

extern "C" void kernel_launch(void* const* d_in, const int* in_sizes, int n_in,
                              void* d_out, int out_size, void* d_ws, size_t ws_size,
                              hipStream_t stream) {
  (void)in_sizes; (void)n_in; (void)out_size; (void)ws_size;
  const float* h0   = (const float*)d_in[1];
  const float* c0   = (const float*)d_in[2];
  const float* cond = (const float*)d_in[3];
  const int*   acts = (const int*)d_in[4];
  const float* durs = (const float*)d_in[5];
  const float* emb  = (const float*)d_in[6];
  const float* ffW  = (const float*)d_in[7];
  const float* ffb  = (const float*)d_in[8];
  const float* Wih  = (const float*)d_in[9];
  const float* Whh  = (const float*)d_in[10];
  const float* bih  = (const float*)d_in[11];
  const float* bhh  = (const float*)d_in[12];
  const float* fcW  = (const float*)d_in[13];
  const float* fcb  = (const float*)d_in[14];

  char* ws = (char*)d_ws;
  size_t off = 0;
  auto alloc = [&](size_t bytes) -> char* {
    char* p0 = ws + off;
    off = (off + bytes + 255) & ~(size_t)255;
    return p0;
  };
  unsigned* slots = (unsigned*)alloc(512 * 64);
  bf16_t* PB1     = (bf16_t*)alloc((size_t)NG * H_ * 2);
  bf16_t* PB2     = (bf16_t*)alloc((size_t)NG * 2048 * 2);
  float*  CHp     = (float*)alloc((size_t)B_ * NG * 4);
  float*  E16p    = (float*)alloc((size_t)16 * NG * 4);
  float*  wcolp   = (float*)alloc((size_t)NG * 4);
  float*  biasBp  = (float*)alloc((size_t)NG * 4);
  float*  G       = (float*)alloc((size_t)33 * NG * 4);
  bf16_t* fcWp    = (bf16_t*)alloc((size_t)17 * H_ * 2);
  bf16_t* pah0i   = (bf16_t*)alloc((size_t)B_ * H_ * 2);
  bf16_t* pah0a   = (bf16_t*)alloc((size_t)B_ * H_ * 2);
  bf16_t* pah0b   = (bf16_t*)alloc((size_t)B_ * H_ * 2);
  bf16_t* pah1a   = (bf16_t*)alloc((size_t)B_ * H_ * 2);
  bf16_t* pah1b   = (bf16_t*)alloc((size_t)B_ * H_ * 2);
  float*  preds   = (float*)alloc((size_t)T_ * B_ * NOUT * 4);

  hipMemsetAsync(slots, 0, 512 * 64, stream);
  hipMemsetAsync(preds, 0, (size_t)T_ * B_ * NOUT * 4, stream);
  k_pack_wA<<<2048, 256, 0, stream>>>(Whh, PB1);
  k_pack_wB<<<4096, 256, 0, stream>>>(Wih + (size_t)NG * H_, Whh + (size_t)NG * H_, PB2);
  k_G<<<16, 256, 0, stream>>>(Wih, ffW, ffb, G);
  k_CHp<<<8192, 256, 0, stream>>>(cond, G, bih, bhh, CHp);
  k_E16<<<256, 256, 0, stream>>>(emb, Wih, E16p);
  k_misc<<<68, 256, 0, stream>>>(Wih, bih, bhh, fcW, fcWp, biasBp, wcolp);
  k_init<<<256, 256, 0, stream>>>(h0, pah0i, pah1a);

  Params prm;
  prm.acts = acts; prm.durs = durs;
  prm.PB1 = PB1; prm.PB2 = PB2;
  prm.CHp = CHp; prm.E16p = E16p; prm.wcolp = wcolp; prm.biasBp = biasBp;
  prm.fcW = fcWp;
  prm.c0in = c0;
  prm.pah0i = pah0i;
  prm.pah0a = pah0a; prm.pah0b = pah0b; prm.pah1a = pah1a; prm.pah1b = pah1b;
  prm.slots = slots; prm.preds = preds;

  lstm_main<<<dim3(512), dim3(256), 0, stream>>>(prm);
  k_out<<<(T_ * B_ + 255) / 256, 256, 0, stream>>>(preds, fcb, (float*)d_out);
}

// Round 9
// 11055.969 us; speedup vs baseline: 1.0018x; 1.0018x over previous
//
#include <hip/hip_runtime.h>
#include <hip/hip_bf16.h>
#include <stdint.h>

#define B_   512
#define H_   1024
#define T_   144
#define NG   4096
#define NOUT 17

typedef __bf16 bf16_t;
typedef __bf16 bf16x8 __attribute__((ext_vector_type(8)));
typedef float  f32x4  __attribute__((ext_vector_type(4)));

__device__ __host__ __forceinline__ int npack(int n) {
  int g = n >> 10, j = n & 1023;
  return ((j >> 4) << 6) + (g << 4) + (j & 15);
}
__device__ __forceinline__ float sigf(float x) { return 1.f / (1.f + __expf(-x)); }
__device__ __forceinline__ float tanhf_(float x) { return 1.f - 2.f / (__expf(2.f * x) + 1.f); }

// ---------------- prep kernels (same layouts as r6-r8) ----------------

__global__ void k_pack_wA(const float* __restrict__ Whh0, bf16_t* __restrict__ PB1) {
  int idx = blockIdx.x * 256 + threadIdx.x;     // 4096*128
  int n = idx >> 7, kc = idx & 127;
  const float* s = Whh0 + (size_t)n * H_ + kc * 8;
  bf16x8 v;
#pragma unroll
  for (int e = 0; e < 8; ++e) v[e] = (bf16_t)s[e];
  int np = npack(n), jt = np >> 6, r = np & 63;
  *(bf16x8*)(PB1 + (size_t)jt * 65536 + (kc >> 2) * 2048 + r * 32 + (kc & 3) * 8) = v;
}

__global__ void k_pack_wB(const float* __restrict__ Wih1, const float* __restrict__ Whh1,
                          bf16_t* __restrict__ PB2) {
  int idx = blockIdx.x * 256 + threadIdx.x;     // 4096*256
  int n = idx >> 8, kc = idx & 255;
  int k = kc * 8;
  const float* s = (k < H_) ? (Wih1 + (size_t)n * H_ + k) : (Whh1 + (size_t)n * H_ + (k - H_));
  bf16x8 v;
#pragma unroll
  for (int e = 0; e < 8; ++e) v[e] = (bf16_t)s[e];
  int np = npack(n), jt = np >> 6, r = np & 63;
  *(bf16x8*)(PB2 + (size_t)jt * 131072 + (kc >> 2) * 2048 + r * 32 + (kc & 3) * 8) = v;
}

__global__ void k_G(const float* __restrict__ Wih0, const float* __restrict__ ffW,
                    const float* __restrict__ ffb, float* __restrict__ G) {
  int n = blockIdx.x * 256 + threadIdx.x;       // 4096
  float acc[33];
#pragma unroll
  for (int c = 0; c < 33; ++c) acc[c] = 0.f;
  for (int k = 0; k < 512; ++k) {
    float wv = Wih0[(size_t)n * H_ + 512 + k];
    const float* fr = ffW + (size_t)k * 32;
#pragma unroll
    for (int c = 0; c < 32; ++c) acc[c] += wv * fr[c];
    acc[32] += wv * ffb[k];
  }
  for (int c = 0; c < 33; ++c) G[(size_t)c * NG + n] = acc[c];
}

__global__ void k_CHp(const float* __restrict__ cond, const float* __restrict__ G,
                      const float* __restrict__ bih0, const float* __restrict__ bhh0,
                      float* __restrict__ CHp) {
  int idx = blockIdx.x * 256 + threadIdx.x;     // 512*4096
  int b = idx >> 12, n = idx & 4095;
  float acc = bih0[n] + bhh0[n] + G[(size_t)32 * NG + n];
  const float* cb = cond + (size_t)b * 32;
#pragma unroll
  for (int c = 0; c < 32; ++c) acc += cb[c] * G[(size_t)c * NG + n];
  CHp[(size_t)b * NG + npack(n)] = acc;
}

__global__ void k_E16(const float* __restrict__ emb, const float* __restrict__ Wih0,
                      float* __restrict__ E16p) {
  int idx = blockIdx.x * 256 + threadIdx.x;     // 16*4096
  int a = idx & 15, n = idx >> 4;
  const float* er = emb + (size_t)a * 511;
  const float* wr = Wih0 + (size_t)n * H_;
  float acc = 0.f;
  for (int k = 0; k < 511; ++k) acc += er[k] * wr[k];
  E16p[(size_t)a * NG + npack(n)] = acc;
}

__global__ void k_misc(const float* __restrict__ Wih0, const float* __restrict__ bih,
                       const float* __restrict__ bhh, const float* __restrict__ fcW,
                       bf16_t* __restrict__ fcWp, float* __restrict__ biasBp,
                       float* __restrict__ wcolp) {
  int idx = blockIdx.x * 256 + threadIdx.x;     // 17408
  if (idx < NG) {
    int np = npack(idx);
    biasBp[np] = bih[NG + idx] + bhh[NG + idx];
    wcolp[np]  = Wih0[(size_t)idx * H_ + 511];
  }
  if (idx < 17 * H_) fcWp[idx] = (bf16_t)fcW[idx];
}

__global__ void k_init(const float* __restrict__ h0,
                       bf16_t* __restrict__ pah0i, bf16_t* __restrict__ h1slot0) {
  int idx = blockIdx.x * 256 + threadIdx.x;     // 512*128
  int b = idx >> 7, kc = idx & 127;
  const float* s0 = h0 + (size_t)b * H_ + kc * 8;
  const float* s1 = s0 + (size_t)B_ * H_;
  bf16x8 v0, v1;
#pragma unroll
  for (int e = 0; e < 8; ++e) { v0[e] = (bf16_t)s0[e]; v1[e] = (bf16_t)s1[e]; }
  size_t po = (size_t)(kc >> 2) * 16384 + b * 32 + (kc & 3) * 8;
  *(bf16x8*)(pah0i + po) = v0;
  *(bf16x8*)(h1slot0 + po) = v1;
}

// ---------------- output finalization ----------------

__global__ void k_out(const float* __restrict__ preds, const float* __restrict__ fcb,
                      float* __restrict__ out) {
  int idx = blockIdx.x * 256 + threadIdx.x;     // T*B
  if (idx >= T_ * B_) return;
  int t = idx % T_, b = idx / T_;
  const float* pr = preds + ((size_t)t * B_ + b) * NOUT;
  float v[NOUT];
#pragma unroll
  for (int o = 0; o < NOUT; ++o) v[o] = pr[o] + fcb[o];
  float m = v[0];
#pragma unroll
  for (int o = 1; o < 16; ++o) m = fmaxf(m, v[o]);
  float s = 0.f;
#pragma unroll
  for (int o = 0; o < 16; ++o) s += expf(v[o] - m);
  float lse = m + logf(s);
  float* dst = out + ((size_t)b * T_ + t) * NOUT;
#pragma unroll
  for (int o = 0; o < 16; ++o) dst[o] = v[o] - lse;
  float x = v[16];
  dst[16] = (x > 0.f) ? -log1pf(expf(-x)) : (x - log1pf(expf(x)));
}

// ---------------- main persistent kernel ----------------

struct Params {
  const int* acts; const float* durs;
  const bf16_t* PB1; const bf16_t* PB2;
  const float* CHp; const float* E16p; const float* wcolp; const float* biasBp;
  const bf16_t* fcW;
  const float* c0in;
  const bf16_t* pah0i;
  bf16_t* h0ring; bf16_t* h1ring;
  unsigned* slots; float* preds;
};

// flag-slot grid barrier, 512 WGs (proven r7/r8)
__device__ __forceinline__ void gbar(unsigned* slots, unsigned phase, int tid, int wg) {
  __syncthreads();
  if (tid == 0) {
    __builtin_amdgcn_fence(__ATOMIC_RELEASE, "agent");   // wbl2: h stores -> LLC
    __hip_atomic_store(slots + (size_t)wg * 16, phase, __ATOMIC_RELAXED, __HIP_MEMORY_SCOPE_AGENT);
  }
  {
    const unsigned* a0 = slots + (size_t)tid * 16;
    const unsigned* a1 = slots + (size_t)(tid + 256) * 16;
    while (__hip_atomic_load(a0, __ATOMIC_RELAXED, __HIP_MEMORY_SCOPE_SYSTEM) < phase)
      __builtin_amdgcn_s_sleep(1);
    while (__hip_atomic_load(a1, __ATOMIC_RELAXED, __HIP_MEMORY_SCOPE_SYSTEM) < phase)
      __builtin_amdgcn_s_sleep(1);
  }
  __syncthreads();
}

// merged-block slot: h0-frag (a), h1-frag (e), W0 (b), W1ih (c), W1hh (d)
struct Slot { bf16x8 a0, e0, b0, b1, b2, b3, c0, c1, c2, c3, d0, d1, d2, d3; };

__device__ __forceinline__ void ldA1byp(bf16x8& r0, const char* p) {
  asm volatile("global_load_dwordx4 %0, %1, off sc0 sc1" : "=&v"(r0) : "v"(p));
}
__device__ __forceinline__ void ldA1pl(bf16x8& r0, const char* p) {
  asm volatile("global_load_dwordx4 %0, %1, off" : "=&v"(r0) : "v"(p));
}
__device__ __forceinline__ void ldB4(bf16x8& r0, bf16x8& r1, bf16x8& r2, bf16x8& r3,
                                     const char* p) {
  asm volatile("global_load_dwordx4 %0, %4, off\n\t"
               "global_load_dwordx4 %1, %4, off offset:1024\n\t"
               "global_load_dwordx4 %2, %4, off offset:2048\n\t"
               "global_load_dwordx4 %3, %4, off offset:3072"
               : "=&v"(r0), "=&v"(r1), "=&v"(r2), "=&v"(r3) : "v"(p));
}

#define VMW(N) { asm volatile("s_waitcnt vmcnt(" #N ")" ::: "memory"); \
                 __builtin_amdgcn_sched_barrier(0); }

#define MFM(ACC, AV, BV) ACC = __builtin_amdgcn_mfma_f32_16x16x32_bf16(AV, BV, ACC, 0, 0, 0)

__device__ __forceinline__ void compS(f32x4 (&A0)[4], f32x4 (&A1)[4], const Slot& S) {
  MFM(A0[0], S.a0, S.b0); MFM(A0[1], S.a0, S.b1);
  MFM(A0[2], S.a0, S.b2); MFM(A0[3], S.a0, S.b3);
  MFM(A1[0], S.a0, S.c0); MFM(A1[1], S.a0, S.c1);
  MFM(A1[2], S.a0, S.c2); MFM(A1[3], S.a0, S.c3);
  MFM(A1[0], S.e0, S.d0); MFM(A1[1], S.e0, S.d1);
  MFM(A1[2], S.e0, S.d2); MFM(A1[3], S.e0, S.d3);
}

__device__ __forceinline__ void compP(f32x4 (&A0)[4], const Slot& S) {
  MFM(A0[0], S.a0, S.b0); MFM(A0[1], S.a0, S.b1);
  MFM(A0[2], S.a0, S.b2); MFM(A0[3], S.a0, S.b3);
}

// R = h-ring depth. R=145: every read address is write-once-read-next-step ->
// plain cached loads are deterministically fresh (producer wbl2 at barrier).
// R=2 fallback (small ws): address reuse -> BYPASS (sc0 sc1) loads as in r8.
template<int R, bool BYPASS>
__global__ __launch_bounds__(256, 2) void lstm_main(Params p) {
  const int tid = threadIdx.x;
  const int w = tid >> 6, l = tid & 63;
  const int wg = blockIdx.x;                 // 512 WGs
  const int mt2 = (wg >> 3) & 7;             // 8 M-tiles of 64 rows
  const int jt = ((wg >> 6) << 3) | (wg & 7);// 64 jt; per XCD: 8 jt x 8 mt
  const int jj = l & 15, rq = l >> 4;
  const int jcol = jt * 16 + jj;
  const int npb = jt * 64;
  const int a_off = (mt2 * 64 + w * 16 + jj) * 64 + rq * 16;  // byte off in kk-block
  const int b_off = jj * 64 + rq * 16;
  const char* Bw0 = (const char*)p.PB1 + (size_t)jt * 131072;
  const char* Bw1 = (const char*)p.PB2 + (size_t)jt * 262144;
  const int he_off = (jcol >> 5) * 16384 + (jcol & 31);
  const size_t SLOT = (size_t)B_ * H_ * 2;   // 1 MB ring slot

  // fc-head rows kept in bf16: lane jj owns output o=jj
  bf16x8 fcw_a, fcw_b, fw16_a, fw16_b;
  {
    const char* fwp = (const char*)p.fcW;
    fcw_a  = *(const bf16x8*)(fwp + jj * 2048 + jt * 32);
    fcw_b  = *(const bf16x8*)(fwp + jj * 2048 + jt * 32 + 16);
    fw16_a = *(const bf16x8*)(fwp + 16 * 2048 + jt * 32);
    fw16_b = *(const bf16x8*)(fwp + 16 * 2048 + jt * 32 + 16);
  }

  // hoisted t-invariant per-thread state: c-state, biases, CHp
  float chv[4][4], cv0[4], cv1[4], bzv[4], wcv[4];
#pragma unroll
  for (int qq = 0; qq < 4; ++qq) {
    int b = mt2 * 64 + w * 16 + rq * 4 + qq;
    cv0[qq] = p.c0in[(size_t)b * H_ + jcol];
    cv1[qq] = p.c0in[(size_t)B_ * H_ + (size_t)b * H_ + jcol];
#pragma unroll
    for (int g = 0; g < 4; ++g)
      chv[qq][g] = p.CHp[(size_t)b * NG + npb + g * 16 + jj];
  }
#pragma unroll
  for (int g = 0; g < 4; ++g) {
    bzv[g] = p.biasBp[npb + g * 16 + jj];
    wcv[g] = p.wcolp[npb + g * 16 + jj];
  }

  Slot S0, S1, S2;

  // ======== prologue: h0^(0) = cell0(x_0, h0_init) -> h0ring slot 0 ========
  {
    f32x4 acc0[4];
#pragma unroll
    for (int g = 0; g < 4; ++g) acc0[g] = (f32x4){0.f, 0.f, 0.f, 0.f};

    const char* Ai = (const char*)p.pah0i;
    auto Pp = [&](int kk, Slot& S) {
      ldA1pl(S.a0, Ai + (size_t)kk * 32768 + a_off);
      ldB4(S.b0, S.b1, S.b2, S.b3, Bw0 + (size_t)kk * 4096 + b_off);
    };
    Pp(0, S0); Pp(1, S1);
#pragma unroll 1
    for (int o = 0; o < 10; ++o) {
      const int k = o * 3;
      Pp(k + 2, S2); VMW(10); compP(acc0, S0);
      Pp(k + 3, S0); VMW(10); compP(acc0, S1);
      Pp(k + 4, S1); VMW(10); compP(acc0, S2);
    }
    VMW(5);  compP(acc0, S0);
    VMW(0);  compP(acc0, S1);

    bf16_t* H0n = p.h0ring;                     // slot 0
#pragma unroll
    for (int qq = 0; qq < 4; ++qq) {
      int b = mt2 * 64 + w * 16 + rq * 4 + qq;
      float pre[4];
#pragma unroll
      for (int g = 0; g < 4; ++g)
        pre[g] = acc0[g][qq] + chv[qq][g] + p.E16p[npb + g * 16 + jj];
      float cn = sigf(pre[1]) * cv0[qq] + sigf(pre[0]) * tanhf_(pre[2]);
      float hn = sigf(pre[3]) * tanhf_(cn);
      cv0[qq] = cn;
      H0n[(size_t)he_off + b * 32] = (bf16_t)hn;
    }
    gbar(p.slots, 1u, tid, wg);
  }

  // ======== main: superstep s computes h1^(s) AND h0^(s+1), one barrier ========
  int rs = 0;                                   // read slot index
#pragma unroll 1
  for (int s = 0; s < T_; ++s) {
    const int wslt = (rs + 1 == R) ? 0 : rs + 1;
    const char* Ah0 = (const char*)p.h0ring + (size_t)rs * SLOT;
    bf16_t*     H0n = p.h0ring + (size_t)wslt * (SLOT / 2);   // bf16 elements
    const char* Ah1 = (const char*)p.h1ring + (size_t)rs * SLOT;
    bf16_t*     H1n = p.h1ring + (size_t)wslt * (SLOT / 2);

    f32x4 acc0[4], acc1[4];
#pragma unroll
    for (int g = 0; g < 4; ++g) {
      acc0[g] = (f32x4){0.f, 0.f, 0.f, 0.f};
      acc1[g] = (f32x4){0.f, 0.f, 0.f, 0.f};
    }

    auto Pm = [&](int kk, Slot& S) {
      if constexpr (BYPASS) {
        ldA1byp(S.a0, Ah0 + (size_t)kk * 32768 + a_off);
        ldA1byp(S.e0, Ah1 + (size_t)kk * 32768 + a_off);
      } else {
        ldA1pl(S.a0, Ah0 + (size_t)kk * 32768 + a_off);
        ldA1pl(S.e0, Ah1 + (size_t)kk * 32768 + a_off);
      }
      ldB4(S.b0, S.b1, S.b2, S.b3, Bw0 + (size_t)kk * 4096 + b_off);
      ldB4(S.c0, S.c1, S.c2, S.c3, Bw1 + (size_t)kk * 4096 + b_off);
      ldB4(S.d0, S.d1, S.d2, S.d3, Bw1 + (size_t)(32 + kk) * 4096 + b_off);
    };
    Pm(0, S0); Pm(1, S1);
#pragma unroll 1
    for (int o = 0; o < 10; ++o) {
      const int k = o * 3;
      Pm(k + 2, S2); VMW(28); compS(acc0, acc1, S0);
      Pm(k + 3, S0); VMW(28); compS(acc0, acc1, S1);
      Pm(k + 4, S1); VMW(28); compS(acc0, acc1, S2);
    }
    VMW(14); compS(acc0, acc1, S0);
    VMW(0);  compS(acc0, acc1, S1);

    // epilogue: cell1 -> h1^(s) + fc head;  cell0 -> h0^(s+1)
#pragma unroll
    for (int qq = 0; qq < 4; ++qq) {
      int b = mt2 * 64 + w * 16 + rq * 4 + qq;
      // ---- layer 1 cell ----
      float pre1[4];
#pragma unroll
      for (int g = 0; g < 4; ++g) pre1[g] = acc1[g][qq] + bzv[g];
      float cn1 = sigf(pre1[1]) * cv1[qq] + sigf(pre1[0]) * tanhf_(pre1[2]);
      float hn1 = sigf(pre1[3]) * tanhf_(cn1);
      cv1[qq] = cn1;
      H1n[(size_t)he_off + b * 32] = (bf16_t)hn1;
      // fc-head partials over this WG's 16 columns
      float accO = 0.f, acc16 = 0.f;
#pragma unroll
      for (int sc = 0; sc < 8; ++sc) {
        float hs = __shfl(hn1, (l & 48) | sc, 64);
        accO  += hs * (float)fcw_a[sc];
        acc16 += hs * (float)fw16_a[sc];
      }
#pragma unroll
      for (int sc = 0; sc < 8; ++sc) {
        float hs = __shfl(hn1, (l & 48) | (8 + sc), 64);
        accO  += hs * (float)fcw_b[sc];
        acc16 += hs * (float)fw16_b[sc];
      }
      float* pb = p.preds + ((size_t)s * B_ + b) * NOUT;
      atomicAdd(pb + jj, accO);
      if (jj == 15) atomicAdd(pb + 16, acc16);
      // ---- layer 0 cell (next step's h0) ----
      int act = p.acts[(size_t)b * T_ + s];
      float dur = p.durs[(size_t)b * T_ + s];
      float pre0[4];
#pragma unroll
      for (int g = 0; g < 4; ++g)
        pre0[g] = acc0[g][qq] + chv[qq][g]
                + p.E16p[(size_t)act * NG + npb + g * 16 + jj] + dur * wcv[g];
      float cn0 = sigf(pre0[1]) * cv0[qq] + sigf(pre0[0]) * tanhf_(pre0[2]);
      float hn0 = sigf(pre0[3]) * tanhf_(cn0);
      cv0[qq] = cn0;
      H0n[(size_t)he_off + b * 32] = (bf16_t)hn0;
    }
    gbar(p.slots, (unsigned)(s + 2), tid, wg);
    rs = wslt;
  }
}

// ---------------- launch ----------------

extern "C" void kernel_launch(void* const* d_in, const int* in_sizes, int n_in,
                              void* d_out, int out_size, void* d_ws, size_t ws_size,
                              hipStream_t stream) {
  (void)in_sizes; (void)n_in; (void)out_size;
  const float* h0   = (const float*)d_in[1];
  const float* c0   = (const float*)d_in[2];
  const float* cond = (const float*)d_in[3];
  const int*   acts = (const int*)d_in[4];
  const float* durs = (const float*)d_in[5];
  const float* emb  = (const float*)d_in[6];
  const float* ffW  = (const float*)d_in[7];
  const float* ffb  = (const float*)d_in[8];
  const float* Wih  = (const float*)d_in[9];
  const float* Whh  = (const float*)d_in[10];
  const float* bih  = (const float*)d_in[11];
  const float* bhh  = (const float*)d_in[12];
  const float* fcW  = (const float*)d_in[13];
  const float* fcb  = (const float*)d_in[14];

  const size_t SLOT = (size_t)B_ * H_ * 2;          // 1 MB
  // fixed allocations ≈ 46.6 MB; ring = 2*R MB
  const size_t fixed = (size_t)(512 * 64) + 8u * 1024 * 1024 + 16u * 1024 * 1024 +
                       (size_t)B_ * NG * 4 + 16u * NG * 4 + NG * 4 + NG * 4 +
                       33u * NG * 4 + 17u * H_ * 2 + SLOT +
                       (size_t)T_ * B_ * NOUT * 4 + 64u * 1024;   // + align slack
  const bool use_ring = ws_size >= fixed + 2u * (T_ + 1) * SLOT;
  const int R = use_ring ? (T_ + 1) : 2;

  char* ws = (char*)d_ws;
  size_t off = 0;
  auto alloc = [&](size_t bytes) -> char* {
    char* p0 = ws + off;
    off = (off + bytes + 255) & ~(size_t)255;
    return p0;
  };
  unsigned* slots = (unsigned*)alloc(512 * 64);
  bf16_t* PB1     = (bf16_t*)alloc((size_t)NG * H_ * 2);
  bf16_t* PB2     = (bf16_t*)alloc((size_t)NG * 2048 * 2);
  float*  CHp     = (float*)alloc((size_t)B_ * NG * 4);
  float*  E16p    = (float*)alloc((size_t)16 * NG * 4);
  float*  wcolp   = (float*)alloc((size_t)NG * 4);
  float*  biasBp  = (float*)alloc((size_t)NG * 4);
  float*  G       = (float*)alloc((size_t)33 * NG * 4);
  bf16_t* fcWp    = (bf16_t*)alloc((size_t)17 * H_ * 2);
  bf16_t* pah0i   = (bf16_t*)alloc(SLOT);
  float*  preds   = (float*)alloc((size_t)T_ * B_ * NOUT * 4);
  bf16_t* h0ring  = (bf16_t*)alloc((size_t)R * SLOT);
  bf16_t* h1ring  = (bf16_t*)alloc((size_t)R * SLOT);

  hipMemsetAsync(slots, 0, 512 * 64, stream);
  hipMemsetAsync(preds, 0, (size_t)T_ * B_ * NOUT * 4, stream);
  k_pack_wA<<<2048, 256, 0, stream>>>(Whh, PB1);
  k_pack_wB<<<4096, 256, 0, stream>>>(Wih + (size_t)NG * H_, Whh + (size_t)NG * H_, PB2);
  k_G<<<16, 256, 0, stream>>>(Wih, ffW, ffb, G);
  k_CHp<<<8192, 256, 0, stream>>>(cond, G, bih, bhh, CHp);
  k_E16<<<256, 256, 0, stream>>>(emb, Wih, E16p);
  k_misc<<<68, 256, 0, stream>>>(Wih, bih, bhh, fcW, fcWp, biasBp, wcolp);
  k_init<<<256, 256, 0, stream>>>(h0, pah0i, h1ring);   // h1 ring slot 0

  Params prm;
  prm.acts = acts; prm.durs = durs;
  prm.PB1 = PB1; prm.PB2 = PB2;
  prm.CHp = CHp; prm.E16p = E16p; prm.wcolp = wcolp; prm.biasBp = biasBp;
  prm.fcW = fcWp;
  prm.c0in = c0;
  prm.pah0i = pah0i;
  prm.h0ring = h0ring; prm.h1ring = h1ring;
  prm.slots = slots; prm.preds = preds;

  if (use_ring)
    lstm_main<T_ + 1, false><<<dim3(512), dim3(256), 0, stream>>>(prm);
  else
    lstm_main<2, true><<<dim3(512), dim3(256), 0, stream>>>(prm);
  k_out<<<(T_ * B_ + 255) / 256, 256, 0, stream>>>(preds, fcb, (float*)d_out);
}

// Round 12
// 6488.720 us; speedup vs baseline: 1.7069x; 1.7039x over previous
//
#include <hip/hip_runtime.h>
#include <hip/hip_bf16.h>
#include <stdint.h>

#define B_   512
#define H_   1024
#define T_   144
#define NG   4096
#define NOUT 17

typedef __bf16 bf16_t;
typedef __bf16 bf16x8 __attribute__((ext_vector_type(8)));
typedef float  f32x4  __attribute__((ext_vector_type(4)));

__device__ __host__ __forceinline__ int npack(int n) {
  int g = n >> 10, j = n & 1023;
  return ((j >> 4) << 6) + (g << 4) + (j & 15);
}
__device__ __forceinline__ float sigf(float x) { return 1.f / (1.f + __expf(-x)); }
__device__ __forceinline__ float tanhf_(float x) { return 1.f - 2.f / (__expf(2.f * x) + 1.f); }

// ---------------- prep kernels ----------------
// B layout: per (jt of 32, kk): 8KB chunk = 128 rows x 64B.
//   PB1[jt][kk 0..31], PB2[jt][kk 0..63] (ih 0..31, hh 32..63)
//   element off = jt*CH + kk*4096 + row*32 + seg*8   (row = np&127, seg = kc&3)

__global__ void k_pack_wA(const float* __restrict__ Whh0, bf16_t* __restrict__ PB1) {
  int idx = blockIdx.x * 256 + threadIdx.x;     // 4096*128
  int n = idx >> 7, kc = idx & 127;
  const float* s = Whh0 + (size_t)n * H_ + kc * 8;
  bf16x8 v;
#pragma unroll
  for (int e = 0; e < 8; ++e) v[e] = (bf16_t)s[e];
  int np = npack(n), jt = np >> 7, row = np & 127;
  *(bf16x8*)(PB1 + (size_t)jt * 131072 + (kc >> 2) * 4096 + row * 32 + (kc & 3) * 8) = v;
}

__global__ void k_pack_wB(const float* __restrict__ Wih1, const float* __restrict__ Whh1,
                          bf16_t* __restrict__ PB2) {
  int idx = blockIdx.x * 256 + threadIdx.x;     // 4096*256
  int n = idx >> 8, kc = idx & 255;
  int k = kc * 8;
  const float* s = (k < H_) ? (Wih1 + (size_t)n * H_ + k) : (Whh1 + (size_t)n * H_ + (k - H_));
  bf16x8 v;
#pragma unroll
  for (int e = 0; e < 8; ++e) v[e] = (bf16_t)s[e];
  int np = npack(n), jt = np >> 7, row = np & 127;
  *(bf16x8*)(PB2 + (size_t)jt * 262144 + (kc >> 2) * 4096 + row * 32 + (kc & 3) * 8) = v;
}

__global__ void k_G(const float* __restrict__ Wih0, const float* __restrict__ ffW,
                    const float* __restrict__ ffb, float* __restrict__ G) {
  int n = blockIdx.x * 256 + threadIdx.x;       // 4096
  float acc[33];
#pragma unroll
  for (int c = 0; c < 33; ++c) acc[c] = 0.f;
  for (int k = 0; k < 512; ++k) {
    float wv = Wih0[(size_t)n * H_ + 512 + k];
    const float* fr = ffW + (size_t)k * 32;
#pragma unroll
    for (int c = 0; c < 32; ++c) acc[c] += wv * fr[c];
    acc[32] += wv * ffb[k];
  }
  for (int c = 0; c < 33; ++c) G[(size_t)c * NG + n] = acc[c];
}

__global__ void k_CHp(const float* __restrict__ cond, const float* __restrict__ G,
                      const float* __restrict__ bih0, const float* __restrict__ bhh0,
                      float* __restrict__ CHp) {
  int idx = blockIdx.x * 256 + threadIdx.x;     // 512*4096
  int b = idx >> 12, n = idx & 4095;
  float acc = bih0[n] + bhh0[n] + G[(size_t)32 * NG + n];
  const float* cb = cond + (size_t)b * 32;
#pragma unroll
  for (int c = 0; c < 32; ++c) acc += cb[c] * G[(size_t)c * NG + n];
  CHp[(size_t)b * NG + npack(n)] = acc;
}

__global__ void k_E16(const float* __restrict__ emb, const float* __restrict__ Wih0,
                      float* __restrict__ E16p) {
  int idx = blockIdx.x * 256 + threadIdx.x;     // 16*4096
  int a = idx & 15, n = idx >> 4;
  const float* er = emb + (size_t)a * 511;
  const float* wr = Wih0 + (size_t)n * H_;
  float acc = 0.f;
  for (int k = 0; k < 511; ++k) acc += er[k] * wr[k];
  E16p[(size_t)a * NG + npack(n)] = acc;
}

__global__ void k_misc(const float* __restrict__ Wih0, const float* __restrict__ bih,
                       const float* __restrict__ bhh, const float* __restrict__ fcW,
                       bf16_t* __restrict__ fcWp, float* __restrict__ biasBp,
                       float* __restrict__ wcolp) {
  int idx = blockIdx.x * 256 + threadIdx.x;     // 17408
  if (idx < NG) {
    int np = npack(idx);
    biasBp[np] = bih[NG + idx] + bhh[NG + idx];
    wcolp[np]  = Wih0[(size_t)idx * H_ + 511];
  }
  if (idx < 17 * H_) fcWp[idx] = (bf16_t)fcW[idx];
}

__global__ void k_init(const float* __restrict__ h0,
                       bf16_t* __restrict__ pah0i, bf16_t* __restrict__ pah1a) {
  int idx = blockIdx.x * 256 + threadIdx.x;     // 512*128
  int b = idx >> 7, kc = idx & 127;
  const float* s0 = h0 + (size_t)b * H_ + kc * 8;
  const float* s1 = s0 + (size_t)B_ * H_;
  bf16x8 v0, v1;
#pragma unroll
  for (int e = 0; e < 8; ++e) { v0[e] = (bf16_t)s0[e]; v1[e] = (bf16_t)s1[e]; }
  size_t po = (size_t)(kc >> 2) * 16384 + b * 32 + (kc & 3) * 8;
  *(bf16x8*)(pah0i + po) = v0;
  *(bf16x8*)(pah1a + po) = v1;
}

__global__ void k_out(const float* __restrict__ preds, const float* __restrict__ fcb,
                      float* __restrict__ out) {
  int idx = blockIdx.x * 256 + threadIdx.x;     // T*B
  if (idx >= T_ * B_) return;
  int t = idx % T_, b = idx / T_;
  const float* pr = preds + ((size_t)t * B_ + b) * NOUT;
  float v[NOUT];
#pragma unroll
  for (int o = 0; o < NOUT; ++o) v[o] = pr[o] + fcb[o];
  float m = v[0];
#pragma unroll
  for (int o = 1; o < 16; ++o) m = fmaxf(m, v[o]);
  float s = 0.f;
#pragma unroll
  for (int o = 0; o < 16; ++o) s += expf(v[o] - m);
  float lse = m + logf(s);
  float* dst = out + ((size_t)b * T_ + t) * NOUT;
#pragma unroll
  for (int o = 0; o < 16; ++o) dst[o] = v[o] - lse;
  float x = v[16];
  dst[16] = (x > 0.f) ? -log1pf(expf(-x)) : (x - log1pf(expf(x)));
}

// ---------------- main persistent kernel ----------------

struct Params {
  const int* acts; const float* durs;
  const bf16_t* PB1; const bf16_t* PB2;
  const float* CHp; const float* E16p; const float* wcolp; const float* biasBp;
  const bf16_t* fcW;
  const float* c0in;
  const bf16_t* pah0i;
  bf16_t* pah0a; bf16_t* pah0b; bf16_t* pah1a; bf16_t* pah1b;
  unsigned* slots; float* preds;
};

// 256-WG flag-slot barrier (r3-r10 family, proven)
__device__ __forceinline__ void gbar(unsigned* slots, unsigned phase, int tid, int wg) {
  __syncthreads();
  if (tid == 0) {
    __builtin_amdgcn_fence(__ATOMIC_RELEASE, "agent");
    __hip_atomic_store(slots + (size_t)wg * 16, phase, __ATOMIC_RELAXED, __HIP_MEMORY_SCOPE_AGENT);
  }
  {
    const unsigned* a0 = slots + (size_t)tid * 16;
    while (__hip_atomic_load(a0, __ATOMIC_RELAXED, __HIP_MEMORY_SCOPE_SYSTEM) < phase)
      __builtin_amdgcn_s_sleep(1);
  }
  __syncthreads();
}

struct AF { bf16x8 a, e; };
struct B6 { bf16x8 v0, v1, v2, v3, v4, v5; };
struct PS { bf16x8 a, b0, b1, b2, b3, c0, c1, c2, c3; };

#define VMW(N) { asm volatile("s_waitcnt vmcnt(" #N ")" ::: "memory"); \
                 __builtin_amdgcn_sched_barrier(0); }
#define LGK0   { asm volatile("s_waitcnt lgkmcnt(0)" ::: "memory"); \
                 __builtin_amdgcn_sched_barrier(0); }
#define WGBAR  { __builtin_amdgcn_s_barrier(); __builtin_amdgcn_sched_barrier(0); }

#define MFM(ACC, AV, BV) ACC = __builtin_amdgcn_mfma_f32_16x16x32_bf16(AV, BV, ACC, 0, 0, 0)

// A-fragments: agent-scope (sc1) loads — coherent at the LLC across XCDs,
// served at LLC (not HBM) bandwidth.  (r8/r9 used sc0+sc1 = system scope.)
__device__ __forceinline__ void ldF2(AF& f, const char* pa, const char* pe) {
  asm volatile("global_load_dwordx4 %0, %2, off sc1\n\t"
               "global_load_dwordx4 %1, %3, off sc1"
               : "=&v"(f.a), "=&v"(f.e) : "v"(pa), "v"(pe));
}

// 6 plain 16B loads: thread's 96B share of the 24KB B-panel for one kk.
// NOTE: global offset imm is 13-bit SIGNED (max +4095) -> +4096 needs its own address.
__device__ __forceinline__ void ldB6(B6& r, const char* b1k, const char* b2k, const char* b2k32) {
  asm volatile("global_load_dwordx4 %0, %2, off\n\t"
               "global_load_dwordx4 %1, %3, off"
               : "=&v"(r.v0), "=&v"(r.v1) : "v"(b1k), "v"(b1k + 4096));
  asm volatile("global_load_dwordx4 %0, %2, off\n\t"
               "global_load_dwordx4 %1, %3, off"
               : "=&v"(r.v2), "=&v"(r.v3) : "v"(b2k), "v"(b2k + 4096));
  asm volatile("global_load_dwordx4 %0, %2, off\n\t"
               "global_load_dwordx4 %1, %3, off"
               : "=&v"(r.v4), "=&v"(r.v5) : "v"(b2k32), "v"(b2k32 + 4096));
}

__device__ __forceinline__ void dswr(char* lb, int tid, const B6& r) {
  *(bf16x8*)(lb + tid * 16)         = r.v0;
  *(bf16x8*)(lb + 4096 + tid * 16)  = r.v1;
  *(bf16x8*)(lb + 8192 + tid * 16)  = r.v2;
  *(bf16x8*)(lb + 12288 + tid * 16) = r.v3;
  *(bf16x8*)(lb + 16384 + tid * 16) = r.v4;
  *(bf16x8*)(lb + 20480 + tid * 16) = r.v5;
}

__device__ __forceinline__ void cmpM(f32x4 (&a0)[2][4], f32x4 (&a1)[2][4],
                                     const char* lbR, const AF& f) {
#pragma unroll
  for (int s = 0; s < 2; ++s)
#pragma unroll
    for (int g = 0; g < 4; ++g) {
      bf16x8 w0 = *(const bf16x8*)(lbR + s * 4096 + g * 1024);
      MFM(a0[s][g], f.a, w0);
    }
#pragma unroll
  for (int s = 0; s < 2; ++s)
#pragma unroll
    for (int g = 0; g < 4; ++g) {
      bf16x8 wi = *(const bf16x8*)(lbR + 8192 + s * 4096 + g * 1024);
      MFM(a1[s][g], f.a, wi);
      bf16x8 wh = *(const bf16x8*)(lbR + 16384 + s * 4096 + g * 1024);
      MFM(a1[s][g], f.e, wh);
    }
}

__global__ __launch_bounds__(256, 1) void lstm_main(Params p) {
  __shared__ __align__(16) char smem[3 * 24576];   // 3 bufs: W0(8K)|W1ih(8K)|W1hh(8K)

  const int tid = threadIdx.x;
  const int w = tid >> 6, l = tid & 63;
  const int wg = blockIdx.x;                  // 256 WGs
  const int mt2 = wg >> 5;                    // 8 M-tiles of 64 rows
  const int jt  = ((wg >> 3) & 3) * 8 + (wg & 7);   // 32 jt (4 per XCD)
  const int jj = l & 15, rq = l >> 4;
  const int a_off = (mt2 * 64 + w * 16 + jj) * 64 + rq * 16;   // bytes in kk-block
  const char* B1 = (const char*)p.PB1 + (size_t)jt * 262144;
  const char* B2 = (const char*)p.PB2 + (size_t)jt * 524288;
  const int heb = jt * 16384 + jj;            // element off: + s*16 + b*32
  const int frag_base = jj * 64 + rq * 16;

  // fc-head rows (lane jj owns output o=jj over this WG's 32 cols)
  bf16x8 fcw[2][2], fw16[2][2];
#pragma unroll
  for (int s = 0; s < 2; ++s) {
    const char* fwp = (const char*)p.fcW;
    fcw[s][0]  = *(const bf16x8*)(fwp + jj * 2048 + (jt * 2 + s) * 32);
    fcw[s][1]  = *(const bf16x8*)(fwp + jj * 2048 + (jt * 2 + s) * 32 + 16);
    fw16[s][0] = *(const bf16x8*)(fwp + 16 * 2048 + (jt * 2 + s) * 32);
    fw16[s][1] = *(const bf16x8*)(fwp + 16 * 2048 + (jt * 2 + s) * 32 + 16);
  }

  // hoisted t-invariant state
  float chv[2][4][4], cv0[2][4], cv1[2][4], bzv[2][4], wcv[2][4];
#pragma unroll
  for (int s = 0; s < 2; ++s) {
    int npb = (jt * 2 + s) * 64;
#pragma unroll
    for (int qq = 0; qq < 4; ++qq) {
      int b = mt2 * 64 + w * 16 + rq * 4 + qq;
      int jcol = (jt * 2 + s) * 16 + jj;
      cv0[s][qq] = p.c0in[(size_t)b * H_ + jcol];
      cv1[s][qq] = p.c0in[(size_t)B_ * H_ + (size_t)b * H_ + jcol];
#pragma unroll
      for (int g = 0; g < 4; ++g)
        chv[s][qq][g] = p.CHp[(size_t)b * NG + npb + g * 16 + jj];
    }
#pragma unroll
    for (int g = 0; g < 4; ++g) {
      bzv[s][g] = p.biasBp[npb + g * 16 + jj];
      wcv[s][g] = p.wcolp[npb + g * 16 + jj];
    }
  }
  VMW(0);   // drain hoisted loads: counted waits below assume a clean vmcnt

  unsigned phase = 0;

  // ======== prologue GEMM: h0^(0) = cell0(x_0, h0_init); register path ========
  {
    f32x4 acc0[2][4];
#pragma unroll
    for (int s = 0; s < 2; ++s)
#pragma unroll
      for (int g = 0; g < 4; ++g) acc0[s][g] = (f32x4){0.f, 0.f, 0.f, 0.f};

    const char* Ai = (const char*)p.pah0i;
    PS S0, S1, S2;
    auto Pp = [&](int kk, PS& S) {       // 9 vm-ops
      asm volatile("global_load_dwordx4 %0, %1, off"
                   : "=&v"(S.a) : "v"(Ai + (size_t)kk * 32768 + a_off));
      const char* p0 = B1 + (size_t)kk * 8192 + frag_base;
      asm volatile("global_load_dwordx4 %0, %4, off\n\t"
                   "global_load_dwordx4 %1, %4, off offset:1024\n\t"
                   "global_load_dwordx4 %2, %4, off offset:2048\n\t"
                   "global_load_dwordx4 %3, %4, off offset:3072"
                   : "=&v"(S.b0), "=&v"(S.b1), "=&v"(S.b2), "=&v"(S.b3) : "v"(p0));
      const char* p1 = p0 + 4096;
      asm volatile("global_load_dwordx4 %0, %4, off\n\t"
                   "global_load_dwordx4 %1, %4, off offset:1024\n\t"
                   "global_load_dwordx4 %2, %4, off offset:2048\n\t"
                   "global_load_dwordx4 %3, %4, off offset:3072"
                   : "=&v"(S.c0), "=&v"(S.c1), "=&v"(S.c2), "=&v"(S.c3) : "v"(p1));
    };
    auto Cp = [&](const PS& S) {         // 8 MFMA
      MFM(acc0[0][0], S.a, S.b0); MFM(acc0[0][1], S.a, S.b1);
      MFM(acc0[0][2], S.a, S.b2); MFM(acc0[0][3], S.a, S.b3);
      MFM(acc0[1][0], S.a, S.c0); MFM(acc0[1][1], S.a, S.c1);
      MFM(acc0[1][2], S.a, S.c2); MFM(acc0[1][3], S.a, S.c3);
    };
    Pp(0, S0); Pp(1, S1);
#pragma unroll 1
    for (int o = 0; o < 10; ++o) {
      Pp(3 * o + 2, S2); VMW(18); Cp(S0);
      Pp(3 * o + 3, S0); VMW(18); Cp(S1);
      Pp(3 * o + 4, S1); VMW(18); Cp(S2);   // o=9 stages kk=31
    }
    VMW(9); Cp(S0);    // kk=30
    VMW(0); Cp(S1);    // kk=31

    bf16_t* H0n = p.pah0a;
#pragma unroll
    for (int s = 0; s < 2; ++s)
#pragma unroll
      for (int qq = 0; qq < 4; ++qq) {
        int b = mt2 * 64 + w * 16 + rq * 4 + qq;
        int npb = (jt * 2 + s) * 64;
        float pre[4];
#pragma unroll
        for (int g = 0; g < 4; ++g)
          pre[g] = acc0[s][g][qq] + chv[s][qq][g] + p.E16p[npb + g * 16 + jj];
        float cn = sigf(pre[1]) * cv0[s][qq] + sigf(pre[0]) * tanhf_(pre[2]);
        float hn = sigf(pre[3]) * tanhf_(cn);
        cv0[s][qq] = cn;
        H0n[(size_t)heb + s * 16 + b * 32] = (bf16_t)hn;
      }
    ++phase; gbar(p.slots, phase, tid, wg);
  }

  // ======== main: superstep t -> h1^(t) and h0^(t+1); one grid barrier ========
#pragma unroll 1
  for (int t = 0; t < T_; ++t) {
    const char* Ah0 = (const char*)((t & 1) ? p.pah0b : p.pah0a);
    bf16_t*     H0n = (t & 1) ? p.pah0a : p.pah0b;
    const char* Ah1 = (const char*)((t & 1) ? p.pah1b : p.pah1a);
    bf16_t*     H1n = (t & 1) ? p.pah1a : p.pah1b;

    f32x4 acc0[2][4], acc1[2][4];
#pragma unroll
    for (int s = 0; s < 2; ++s)
#pragma unroll
      for (int g = 0; g < 4; ++g) {
        acc0[s][g] = (f32x4){0.f, 0.f, 0.f, 0.f};
        acc1[s][g] = (f32x4){0.f, 0.f, 0.f, 0.f};
      }

    B6 Br0, Br1;
    AF F0, F1;
    auto LB = [&](B6& r, int kk) {
      ldB6(r, B1 + (size_t)kk * 8192 + tid * 16,
              B2 + (size_t)kk * 8192 + tid * 16,
              B2 + (size_t)(kk + 32) * 8192 + tid * 16);
    };
    auto LA = [&](AF& f, int kk) {
      ldF2(f, Ah0 + (size_t)kk * 32768 + a_off, Ah1 + (size_t)kk * 32768 + a_off);
    };

    // pipeline prologue: B(0),B(1),A(0),A(1); write buf0; issue B(2)
    LB(Br0, 0); LB(Br1, 1); LA(F0, 0); LA(F1, 1);
    VMW(10);                    // B(0) arrived (16 outstanding -> oldest 6 done)
    dswr(smem, tid, Br0);
    LB(Br0, 2);
    int bufR = 0;

    // uniform body per kk: VMW(8) [B(kk+1)+A(kk) done] ; write buf(kk+1) ;
    // load B(kk+3) ; LGK0 ; barrier ; MFMA(kk) ; load A(kk+2)
#pragma unroll 1
    for (int kk = 0; kk < 28; kk += 2) {
      {  // even sub-iter: F0, Br1
        int bw = bufR + 1; if (bw == 3) bw = 0;
        VMW(8);
        dswr(smem + bw * 24576, tid, Br1);
        LB(Br1, kk + 3);
        LGK0; WGBAR;
        cmpM(acc0, acc1, smem + bufR * 24576 + frag_base, F0);
        LA(F0, kk + 2);
        bufR = bw;
      }
      {  // odd sub-iter: F1, Br0
        int bw = bufR + 1; if (bw == 3) bw = 0;
        VMW(8);
        dswr(smem + bw * 24576, tid, Br0);
        LB(Br0, kk + 4);
        LGK0; WGBAR;
        cmpM(acc0, acc1, smem + bufR * 24576 + frag_base, F1);
        LA(F1, kk + 3);
        bufR = bw;
      }
    }
    {  // kk = 28 (even): full body, B(31), A(30)
      int bw = bufR + 1; if (bw == 3) bw = 0;
      VMW(8);
      dswr(smem + bw * 24576, tid, Br1);
      LB(Br1, 31);
      LGK0; WGBAR;
      cmpM(acc0, acc1, smem + bufR * 24576 + frag_base, F0);
      LA(F0, 30);
      bufR = bw;
    }
    {  // kk = 29: no B-load; A(31)
      int bw = bufR + 1; if (bw == 3) bw = 0;
      VMW(8);
      dswr(smem + bw * 24576, tid, Br0);
      LGK0; WGBAR;
      cmpM(acc0, acc1, smem + bufR * 24576 + frag_base, F1);
      LA(F1, 31);
      bufR = bw;
    }
    {  // kk = 30: write B(31); outstanding B(31)6+A(30)2+A(31)2=10 -> VMW(2)
      int bw = bufR + 1; if (bw == 3) bw = 0;
      VMW(2);
      dswr(smem + bw * 24576, tid, Br1);
      LGK0; WGBAR;
      cmpM(acc0, acc1, smem + bufR * 24576 + frag_base, F0);
      bufR = bw;
    }
    {  // kk = 31: buf already barriered at kk=30
      VMW(0);
      cmpM(acc0, acc1, smem + bufR * 24576 + frag_base, F1);
    }

    // epilogue: cell1 -> h1^(t) + fc head;  cell0 -> h0^(t+1)
#pragma unroll
    for (int qq = 0; qq < 4; ++qq) {
      int b = mt2 * 64 + w * 16 + rq * 4 + qq;
      int act = p.acts[(size_t)b * T_ + t];
      float dur = p.durs[(size_t)b * T_ + t];
      float hn1v[2];
#pragma unroll
      for (int s = 0; s < 2; ++s) {
        int npb = (jt * 2 + s) * 64;
        float pre1[4];
#pragma unroll
        for (int g = 0; g < 4; ++g) pre1[g] = acc1[s][g][qq] + bzv[s][g];
        float cn1 = sigf(pre1[1]) * cv1[s][qq] + sigf(pre1[0]) * tanhf_(pre1[2]);
        float hn1 = sigf(pre1[3]) * tanhf_(cn1);
        cv1[s][qq] = cn1;
        H1n[(size_t)heb + s * 16 + b * 32] = (bf16_t)hn1;
        hn1v[s] = hn1;
        float pre0[4];
#pragma unroll
        for (int g = 0; g < 4; ++g)
          pre0[g] = acc0[s][g][qq] + chv[s][qq][g]
                  + p.E16p[(size_t)act * NG + npb + g * 16 + jj] + dur * wcv[s][g];
        float cn0 = sigf(pre0[1]) * cv0[s][qq] + sigf(pre0[0]) * tanhf_(pre0[2]);
        float hn0 = sigf(pre0[3]) * tanhf_(cn0);
        cv0[s][qq] = cn0;
        H0n[(size_t)heb + s * 16 + b * 32] = (bf16_t)hn0;
      }
      float accO = 0.f, acc16 = 0.f;
      int base = l & 48;
#pragma unroll
      for (int s = 0; s < 2; ++s) {
#pragma unroll
        for (int sc = 0; sc < 8; ++sc) {
          float hs = __shfl(hn1v[s], base | sc, 64);
          accO  += hs * (float)fcw[s][0][sc];
          acc16 += hs * (float)fw16[s][0][sc];
        }
#pragma unroll
        for (int sc = 0; sc < 8; ++sc) {
          float hs = __shfl(hn1v[s], base | (8 + sc), 64);
          accO  += hs * (float)fcw[s][1][sc];
          acc16 += hs * (float)fw16[s][1][sc];
        }
      }
      float* pb = p.preds + ((size_t)t * B_ + b) * NOUT;
      atomicAdd(pb + jj, accO);
      if (jj == 15) atomicAdd(pb + 16, acc16);
    }
    ++phase; gbar(p.slots, phase, tid, wg);
  }
}

// ---------------- launch ----------------

extern "C" void kernel_launch(void* const* d_in, const int* in_sizes, int n_in,
                              void* d_out, int out_size, void* d_ws, size_t ws_size,
                              hipStream_t stream) {
  (void)in_sizes; (void)n_in; (void)out_size; (void)ws_size;
  const float* h0   = (const float*)d_in[1];
  const float* c0   = (const float*)d_in[2];
  const float* cond = (const float*)d_in[3];
  const int*   acts = (const int*)d_in[4];
  const float* durs = (const float*)d_in[5];
  const float* emb  = (const float*)d_in[6];
  const float* ffW  = (const float*)d_in[7];
  const float* ffb  = (const float*)d_in[8];
  const float* Wih  = (const float*)d_in[9];
  const float* Whh  = (const float*)d_in[10];
  const float* bih  = (const float*)d_in[11];
  const float* bhh  = (const float*)d_in[12];
  const float* fcW  = (const float*)d_in[13];
  const float* fcb  = (const float*)d_in[14];

  char* ws = (char*)d_ws;
  size_t off = 0;
  auto alloc = [&](size_t bytes) -> char* {
    char* p0 = ws + off;
    off = (off + bytes + 255) & ~(size_t)255;
    return p0;
  };
  unsigned* slots = (unsigned*)alloc(256 * 64);
  bf16_t* PB1     = (bf16_t*)alloc((size_t)NG * H_ * 2);
  bf16_t* PB2     = (bf16_t*)alloc((size_t)NG * 2048 * 2);
  float*  CHp     = (float*)alloc((size_t)B_ * NG * 4);
  float*  E16p    = (float*)alloc((size_t)16 * NG * 4);
  float*  wcolp   = (float*)alloc((size_t)NG * 4);
  float*  biasBp  = (float*)alloc((size_t)NG * 4);
  float*  G       = (float*)alloc((size_t)33 * NG * 4);
  bf16_t* fcWp    = (bf16_t*)alloc((size_t)17 * H_ * 2);
  bf16_t* pah0i   = (bf16_t*)alloc((size_t)B_ * H_ * 2);
  bf16_t* pah0a   = (bf16_t*)alloc((size_t)B_ * H_ * 2);
  bf16_t* pah0b   = (bf16_t*)alloc((size_t)B_ * H_ * 2);
  bf16_t* pah1a   = (bf16_t*)alloc((size_t)B_ * H_ * 2);
  bf16_t* pah1b   = (bf16_t*)alloc((size_t)B_ * H_ * 2);
  float*  preds   = (float*)alloc((size_t)T_ * B_ * NOUT * 4);

  hipMemsetAsync(slots, 0, 256 * 64, stream);
  hipMemsetAsync(preds, 0, (size_t)T_ * B_ * NOUT * 4, stream);
  k_pack_wA<<<2048, 256, 0, stream>>>(Whh, PB1);
  k_pack_wB<<<4096, 256, 0, stream>>>(Wih + (size_t)NG * H_, Whh + (size_t)NG * H_, PB2);
  k_G<<<16, 256, 0, stream>>>(Wih, ffW, ffb, G);
  k_CHp<<<8192, 256, 0, stream>>>(cond, G, bih, bhh, CHp);
  k_E16<<<256, 256, 0, stream>>>(emb, Wih, E16p);
  k_misc<<<68, 256, 0, stream>>>(Wih, bih, bhh, fcW, fcWp, biasBp, wcolp);
  k_init<<<256, 256, 0, stream>>>(h0, pah0i, pah1a);

  Params prm;
  prm.acts = acts; prm.durs = durs;
  prm.PB1 = PB1; prm.PB2 = PB2;
  prm.CHp = CHp; prm.E16p = E16p; prm.wcolp = wcolp; prm.biasBp = biasBp;
  prm.fcW = fcWp;
  prm.c0in = c0;
  prm.pah0i = pah0i;
  prm.pah0a = pah0a; prm.pah0b = pah0b; prm.pah1a = pah1a; prm.pah1b = pah1b;
  prm.slots = slots; prm.preds = preds;

  lstm_main<<<dim3(256), dim3(256), 0, stream>>>(prm);
  k_out<<<(T_ * B_ + 255) / 256, 256, 0, stream>>>(preds, fcb, (float*)d_out);
}

// Round 13
// 6313.326 us; speedup vs baseline: 1.7543x; 1.0278x over previous
//
#include <hip/hip_runtime.h>
#include <hip/hip_bf16.h>
#include <stdint.h>

#define B_   512
#define H_   1024
#define T_   144
#define NG   4096
#define NOUT 17

typedef __bf16 bf16_t;
typedef __bf16 bf16x8 __attribute__((ext_vector_type(8)));
typedef float  f32x4  __attribute__((ext_vector_type(4)));

__device__ __host__ __forceinline__ int npack(int n) {
  int g = n >> 10, j = n & 1023;
  return ((j >> 4) << 6) + (g << 4) + (j & 15);
}
__device__ __forceinline__ float sigf(float x) { return 1.f / (1.f + __expf(-x)); }
__device__ __forceinline__ float tanhf_(float x) { return 1.f - 2.f / (__expf(2.f * x) + 1.f); }

// ---------------- prep kernels ----------------
// B layout: per (jt of 32, kk): 8KB chunk = 128 rows x 64B, with seg XOR-swizzle
//   ss = seg ^ ((row>>1)&3)  (bijective within each row) so that the in-kernel
//   stride-64B ds_read_b128 pattern hits all 8 four-bank groups per 8 lanes.
//   element off = jt*CH + kk*4096 + row*32 + ss*8   (row = np&127, seg = kc&3)

__global__ void k_pack_wA(const float* __restrict__ Whh0, bf16_t* __restrict__ PB1) {
  int idx = blockIdx.x * 256 + threadIdx.x;     // 4096*128
  int n = idx >> 7, kc = idx & 127;
  const float* s = Whh0 + (size_t)n * H_ + kc * 8;
  bf16x8 v;
#pragma unroll
  for (int e = 0; e < 8; ++e) v[e] = (bf16_t)s[e];
  int np = npack(n), jt = np >> 7, row = np & 127;
  int ss = (kc & 3) ^ ((row >> 1) & 3);
  *(bf16x8*)(PB1 + (size_t)jt * 131072 + (kc >> 2) * 4096 + row * 32 + ss * 8) = v;
}

__global__ void k_pack_wB(const float* __restrict__ Wih1, const float* __restrict__ Whh1,
                          bf16_t* __restrict__ PB2) {
  int idx = blockIdx.x * 256 + threadIdx.x;     // 4096*256
  int n = idx >> 8, kc = idx & 255;
  int k = kc * 8;
  const float* s = (k < H_) ? (Wih1 + (size_t)n * H_ + k) : (Whh1 + (size_t)n * H_ + (k - H_));
  bf16x8 v;
#pragma unroll
  for (int e = 0; e < 8; ++e) v[e] = (bf16_t)s[e];
  int np = npack(n), jt = np >> 7, row = np & 127;
  int ss = (kc & 3) ^ ((row >> 1) & 3);
  *(bf16x8*)(PB2 + (size_t)jt * 262144 + (kc >> 2) * 4096 + row * 32 + ss * 8) = v;
}

__global__ void k_G(const float* __restrict__ Wih0, const float* __restrict__ ffW,
                    const float* __restrict__ ffb, float* __restrict__ G) {
  int n = blockIdx.x * 256 + threadIdx.x;       // 4096
  float acc[33];
#pragma unroll
  for (int c = 0; c < 33; ++c) acc[c] = 0.f;
  for (int k = 0; k < 512; ++k) {
    float wv = Wih0[(size_t)n * H_ + 512 + k];
    const float* fr = ffW + (size_t)k * 32;
#pragma unroll
    for (int c = 0; c < 32; ++c) acc[c] += wv * fr[c];
    acc[32] += wv * ffb[k];
  }
  for (int c = 0; c < 33; ++c) G[(size_t)c * NG + n] = acc[c];
}

__global__ void k_CHp(const float* __restrict__ cond, const float* __restrict__ G,
                      const float* __restrict__ bih0, const float* __restrict__ bhh0,
                      float* __restrict__ CHp) {
  int idx = blockIdx.x * 256 + threadIdx.x;     // 512*4096
  int b = idx >> 12, n = idx & 4095;
  float acc = bih0[n] + bhh0[n] + G[(size_t)32 * NG + n];
  const float* cb = cond + (size_t)b * 32;
#pragma unroll
  for (int c = 0; c < 32; ++c) acc += cb[c] * G[(size_t)c * NG + n];
  CHp[(size_t)b * NG + npack(n)] = acc;
}

__global__ void k_E16(const float* __restrict__ emb, const float* __restrict__ Wih0,
                      float* __restrict__ E16p) {
  int idx = blockIdx.x * 256 + threadIdx.x;     // 16*4096
  int a = idx & 15, n = idx >> 4;
  const float* er = emb + (size_t)a * 511;
  const float* wr = Wih0 + (size_t)n * H_;
  float acc = 0.f;
  for (int k = 0; k < 511; ++k) acc += er[k] * wr[k];
  E16p[(size_t)a * NG + npack(n)] = acc;
}

__global__ void k_misc(const float* __restrict__ Wih0, const float* __restrict__ bih,
                       const float* __restrict__ bhh, const float* __restrict__ fcW,
                       bf16_t* __restrict__ fcWp, float* __restrict__ biasBp,
                       float* __restrict__ wcolp) {
  int idx = blockIdx.x * 256 + threadIdx.x;     // 17408
  if (idx < NG) {
    int np = npack(idx);
    biasBp[np] = bih[NG + idx] + bhh[NG + idx];
    wcolp[np]  = Wih0[(size_t)idx * H_ + 511];
  }
  if (idx < 17 * H_) fcWp[idx] = (bf16_t)fcW[idx];
}

__global__ void k_init(const float* __restrict__ h0,
                       bf16_t* __restrict__ pah0i, bf16_t* __restrict__ pah1a) {
  int idx = blockIdx.x * 256 + threadIdx.x;     // 512*128
  int b = idx >> 7, kc = idx & 127;
  const float* s0 = h0 + (size_t)b * H_ + kc * 8;
  const float* s1 = s0 + (size_t)B_ * H_;
  bf16x8 v0, v1;
#pragma unroll
  for (int e = 0; e < 8; ++e) { v0[e] = (bf16_t)s0[e]; v1[e] = (bf16_t)s1[e]; }
  size_t po = (size_t)(kc >> 2) * 16384 + b * 32 + (kc & 3) * 8;
  *(bf16x8*)(pah0i + po) = v0;
  *(bf16x8*)(pah1a + po) = v1;
}

__global__ void k_out(const float* __restrict__ preds, const float* __restrict__ fcb,
                      float* __restrict__ out) {
  int idx = blockIdx.x * 256 + threadIdx.x;     // T*B
  if (idx >= T_ * B_) return;
  int t = idx % T_, b = idx / T_;
  const float* pr = preds + ((size_t)t * B_ + b) * NOUT;
  float v[NOUT];
#pragma unroll
  for (int o = 0; o < NOUT; ++o) v[o] = pr[o] + fcb[o];
  float m = v[0];
#pragma unroll
  for (int o = 1; o < 16; ++o) m = fmaxf(m, v[o]);
  float s = 0.f;
#pragma unroll
  for (int o = 0; o < 16; ++o) s += expf(v[o] - m);
  float lse = m + logf(s);
  float* dst = out + ((size_t)b * T_ + t) * NOUT;
#pragma unroll
  for (int o = 0; o < 16; ++o) dst[o] = v[o] - lse;
  float x = v[16];
  dst[16] = (x > 0.f) ? -log1pf(expf(-x)) : (x - log1pf(expf(x)));
}

// ---------------- main persistent kernel ----------------

struct Params {
  const int* acts; const float* durs;
  const bf16_t* PB1; const bf16_t* PB2;
  const float* CHp; const float* E16p; const float* wcolp; const float* biasBp;
  const bf16_t* fcW;
  const float* c0in;
  const bf16_t* pah0i;
  bf16_t* pah0a; bf16_t* pah0b; bf16_t* pah1a; bf16_t* pah1b;
  unsigned* slots; float* preds;
};

// 256-WG flag-slot barrier (r3-r12 family, proven)
__device__ __forceinline__ void gbar(unsigned* slots, unsigned phase, int tid, int wg) {
  __syncthreads();
  if (tid == 0) {
    __builtin_amdgcn_fence(__ATOMIC_RELEASE, "agent");
    __hip_atomic_store(slots + (size_t)wg * 16, phase, __ATOMIC_RELAXED, __HIP_MEMORY_SCOPE_AGENT);
  }
  {
    const unsigned* a0 = slots + (size_t)tid * 16;
    while (__hip_atomic_load(a0, __ATOMIC_RELAXED, __HIP_MEMORY_SCOPE_SYSTEM) < phase)
      __builtin_amdgcn_s_sleep(1);
  }
  __syncthreads();
}

struct AF { bf16x8 a, e; };
struct B6 { bf16x8 v0, v1, v2, v3, v4, v5; };
struct PS { bf16x8 a, b0, b1, b2, b3, c0, c1, c2, c3; };

#define VMW(N) { asm volatile("s_waitcnt vmcnt(" #N ")" ::: "memory"); \
                 __builtin_amdgcn_sched_barrier(0); }
#define LGK0   { asm volatile("s_waitcnt lgkmcnt(0)" ::: "memory"); \
                 __builtin_amdgcn_sched_barrier(0); }
#define WGBAR  { __builtin_amdgcn_s_barrier(); __builtin_amdgcn_sched_barrier(0); }

#define MFM(ACC, AV, BV) ACC = __builtin_amdgcn_mfma_f32_16x16x32_bf16(AV, BV, ACC, 0, 0, 0)

// A-fragments: agent-scope (sc1) loads — coherent at the LLC across XCDs.
__device__ __forceinline__ void ldF2(AF& f, const char* pa, const char* pe) {
  asm volatile("global_load_dwordx4 %0, %2, off sc1\n\t"
               "global_load_dwordx4 %1, %3, off sc1"
               : "=&v"(f.a), "=&v"(f.e) : "v"(pa), "v"(pe));
}

// 6 plain 16B loads: thread's 96B share of the 24KB B-panel for one kk.
// (global offset imm is 13-bit SIGNED, max +4095 -> +4096 needs its own address)
__device__ __forceinline__ void ldB6(B6& r, const char* b1k, const char* b2k, const char* b2k32) {
  asm volatile("global_load_dwordx4 %0, %2, off\n\t"
               "global_load_dwordx4 %1, %3, off"
               : "=&v"(r.v0), "=&v"(r.v1) : "v"(b1k), "v"(b1k + 4096));
  asm volatile("global_load_dwordx4 %0, %2, off\n\t"
               "global_load_dwordx4 %1, %3, off"
               : "=&v"(r.v2), "=&v"(r.v3) : "v"(b2k), "v"(b2k + 4096));
  asm volatile("global_load_dwordx4 %0, %2, off\n\t"
               "global_load_dwordx4 %1, %3, off"
               : "=&v"(r.v4), "=&v"(r.v5) : "v"(b2k32), "v"(b2k32 + 4096));
}

__device__ __forceinline__ void dswr(char* lb, int tid, const B6& r) {
  *(bf16x8*)(lb + tid * 16)         = r.v0;
  *(bf16x8*)(lb + 4096 + tid * 16)  = r.v1;
  *(bf16x8*)(lb + 8192 + tid * 16)  = r.v2;
  *(bf16x8*)(lb + 12288 + tid * 16) = r.v3;
  *(bf16x8*)(lb + 16384 + tid * 16) = r.v4;
  *(bf16x8*)(lb + 20480 + tid * 16) = r.v5;
}

__device__ __forceinline__ void cmpM(f32x4 (&a0)[2][4], f32x4 (&a1)[2][4],
                                     const char* lbR, const AF& f) {
#pragma unroll
  for (int s = 0; s < 2; ++s)
#pragma unroll
    for (int g = 0; g < 4; ++g) {
      bf16x8 w0 = *(const bf16x8*)(lbR + s * 4096 + g * 1024);
      MFM(a0[s][g], f.a, w0);
    }
#pragma unroll
  for (int s = 0; s < 2; ++s)
#pragma unroll
    for (int g = 0; g < 4; ++g) {
      bf16x8 wi = *(const bf16x8*)(lbR + 8192 + s * 4096 + g * 1024);
      MFM(a1[s][g], f.a, wi);
      bf16x8 wh = *(const bf16x8*)(lbR + 16384 + s * 4096 + g * 1024);
      MFM(a1[s][g], f.e, wh);
    }
}

__global__ __launch_bounds__(256, 1) void lstm_main(Params p) {
  __shared__ __align__(16) char smem[3 * 24576];   // 3 bufs: W0(8K)|W1ih(8K)|W1hh(8K)

  const int tid = threadIdx.x;
  const int w = tid >> 6, l = tid & 63;
  const int wg = blockIdx.x;                  // 256 WGs
  const int mt2 = wg >> 5;                    // 8 M-tiles of 64 rows
  const int jt  = ((wg >> 3) & 3) * 8 + (wg & 7);   // 32 jt (4 per XCD)
  const int jj = l & 15, rq = l >> 4;
  const int a_off = (mt2 * 64 + w * 16 + jj) * 64 + rq * 16;   // bytes in kk-block
  const char* B1 = (const char*)p.PB1 + (size_t)jt * 262144;
  const char* B2 = (const char*)p.PB2 + (size_t)jt * 524288;
  const int heb = jt * 16384 + jj;            // element off: + s*16 + b*32
  // swizzled B-fragment offset: matches pack-time ss = seg ^ ((row>>1)&3)
  const int frag_base = jj * 64 + ((rq ^ ((jj >> 1) & 3)) * 16);

  // fc-head rows (lane jj owns output o=jj over this WG's 32 cols)
  bf16x8 fcw[2][2], fw16[2][2];
#pragma unroll
  for (int s = 0; s < 2; ++s) {
    const char* fwp = (const char*)p.fcW;
    fcw[s][0]  = *(const bf16x8*)(fwp + jj * 2048 + (jt * 2 + s) * 32);
    fcw[s][1]  = *(const bf16x8*)(fwp + jj * 2048 + (jt * 2 + s) * 32 + 16);
    fw16[s][0] = *(const bf16x8*)(fwp + 16 * 2048 + (jt * 2 + s) * 32);
    fw16[s][1] = *(const bf16x8*)(fwp + 16 * 2048 + (jt * 2 + s) * 32 + 16);
  }

  // hoisted t-invariant state
  float chv[2][4][4], cv0[2][4], cv1[2][4], bzv[2][4], wcv[2][4];
#pragma unroll
  for (int s = 0; s < 2; ++s) {
    int npb = (jt * 2 + s) * 64;
#pragma unroll
    for (int qq = 0; qq < 4; ++qq) {
      int b = mt2 * 64 + w * 16 + rq * 4 + qq;
      int jcol = (jt * 2 + s) * 16 + jj;
      cv0[s][qq] = p.c0in[(size_t)b * H_ + jcol];
      cv1[s][qq] = p.c0in[(size_t)B_ * H_ + (size_t)b * H_ + jcol];
#pragma unroll
      for (int g = 0; g < 4; ++g)
        chv[s][qq][g] = p.CHp[(size_t)b * NG + npb + g * 16 + jj];
    }
#pragma unroll
    for (int g = 0; g < 4; ++g) {
      bzv[s][g] = p.biasBp[npb + g * 16 + jj];
      wcv[s][g] = p.wcolp[npb + g * 16 + jj];
    }
  }
  VMW(0);   // drain hoisted loads: counted waits below assume a clean vmcnt

  unsigned phase = 0;

  // ======== prologue GEMM: h0^(0) = cell0(x_0, h0_init); register path ========
  {
    f32x4 acc0[2][4];
#pragma unroll
    for (int s = 0; s < 2; ++s)
#pragma unroll
      for (int g = 0; g < 4; ++g) acc0[s][g] = (f32x4){0.f, 0.f, 0.f, 0.f};

    const char* Ai = (const char*)p.pah0i;
    PS S0, S1, S2;
    auto Pp = [&](int kk, PS& S) {       // 9 vm-ops
      asm volatile("global_load_dwordx4 %0, %1, off"
                   : "=&v"(S.a) : "v"(Ai + (size_t)kk * 32768 + a_off));
      const char* p0 = B1 + (size_t)kk * 8192 + frag_base;
      asm volatile("global_load_dwordx4 %0, %4, off\n\t"
                   "global_load_dwordx4 %1, %4, off offset:1024\n\t"
                   "global_load_dwordx4 %2, %4, off offset:2048\n\t"
                   "global_load_dwordx4 %3, %4, off offset:3072"
                   : "=&v"(S.b0), "=&v"(S.b1), "=&v"(S.b2), "=&v"(S.b3) : "v"(p0));
      const char* p1 = p0 + 4096;
      asm volatile("global_load_dwordx4 %0, %4, off\n\t"
                   "global_load_dwordx4 %1, %4, off offset:1024\n\t"
                   "global_load_dwordx4 %2, %4, off offset:2048\n\t"
                   "global_load_dwordx4 %3, %4, off offset:3072"
                   : "=&v"(S.c0), "=&v"(S.c1), "=&v"(S.c2), "=&v"(S.c3) : "v"(p1));
    };
    auto Cp = [&](const PS& S) {         // 8 MFMA
      MFM(acc0[0][0], S.a, S.b0); MFM(acc0[0][1], S.a, S.b1);
      MFM(acc0[0][2], S.a, S.b2); MFM(acc0[0][3], S.a, S.b3);
      MFM(acc0[1][0], S.a, S.c0); MFM(acc0[1][1], S.a, S.c1);
      MFM(acc0[1][2], S.a, S.c2); MFM(acc0[1][3], S.a, S.c3);
    };
    Pp(0, S0); Pp(1, S1);
#pragma unroll 1
    for (int o = 0; o < 10; ++o) {
      Pp(3 * o + 2, S2); VMW(18); Cp(S0);
      Pp(3 * o + 3, S0); VMW(18); Cp(S1);
      Pp(3 * o + 4, S1); VMW(18); Cp(S2);   // o=9 stages kk=31
    }
    VMW(9); Cp(S0);    // kk=30
    VMW(0); Cp(S1);    // kk=31

    bf16_t* H0n = p.pah0a;
#pragma unroll
    for (int s = 0; s < 2; ++s)
#pragma unroll
      for (int qq = 0; qq < 4; ++qq) {
        int b = mt2 * 64 + w * 16 + rq * 4 + qq;
        int npb = (jt * 2 + s) * 64;
        float pre[4];
#pragma unroll
        for (int g = 0; g < 4; ++g)
          pre[g] = acc0[s][g][qq] + chv[s][qq][g] + p.E16p[npb + g * 16 + jj];
        float cn = sigf(pre[1]) * cv0[s][qq] + sigf(pre[0]) * tanhf_(pre[2]);
        float hn = sigf(pre[3]) * tanhf_(cn);
        cv0[s][qq] = cn;
        H0n[(size_t)heb + s * 16 + b * 32] = (bf16_t)hn;
      }
    ++phase; gbar(p.slots, phase, tid, wg);
  }

  // ======== main: superstep t -> h1^(t) and h0^(t+1); one grid barrier ========
#pragma unroll 1
  for (int t = 0; t < T_; ++t) {
    const char* Ah0 = (const char*)((t & 1) ? p.pah0b : p.pah0a);
    bf16_t*     H0n = (t & 1) ? p.pah0a : p.pah0b;
    const char* Ah1 = (const char*)((t & 1) ? p.pah1b : p.pah1a);
    bf16_t*     H1n = (t & 1) ? p.pah1a : p.pah1b;

    f32x4 acc0[2][4], acc1[2][4];
#pragma unroll
    for (int s = 0; s < 2; ++s)
#pragma unroll
      for (int g = 0; g < 4; ++g) {
        acc0[s][g] = (f32x4){0.f, 0.f, 0.f, 0.f};
        acc1[s][g] = (f32x4){0.f, 0.f, 0.f, 0.f};
      }

    B6 Br0, Br1;
    AF F0, F1;
    auto LB = [&](B6& r, int kk) {
      ldB6(r, B1 + (size_t)kk * 8192 + tid * 16,
              B2 + (size_t)kk * 8192 + tid * 16,
              B2 + (size_t)(kk + 32) * 8192 + tid * 16);
    };
    auto LA = [&](AF& f, int kk) {
      ldF2(f, Ah0 + (size_t)kk * 32768 + a_off, Ah1 + (size_t)kk * 32768 + a_off);
    };

    // pipeline prologue: B(0),B(1),A(0),A(1); write buf0; issue B(2)
    LB(Br0, 0); LB(Br1, 1); LA(F0, 0); LA(F1, 1);
    VMW(10);                    // B(0) arrived (16 outstanding -> oldest 6 done)
    dswr(smem, tid, Br0);
    LB(Br0, 2);
    int bufR = 0;

    // uniform body per kk: VMW(8) [B(kk+1)+A(kk) done] ; write buf(kk+1) ;
    // load B(kk+3) ; LGK0 ; barrier ; MFMA(kk) ; load A(kk+2)
#pragma unroll 1
    for (int kk = 0; kk < 28; kk += 2) {
      {  // even sub-iter: F0, Br1
        int bw = bufR + 1; if (bw == 3) bw = 0;
        VMW(8);
        dswr(smem + bw * 24576, tid, Br1);
        LB(Br1, kk + 3);
        LGK0; WGBAR;
        cmpM(acc0, acc1, smem + bufR * 24576 + frag_base, F0);
        LA(F0, kk + 2);
        bufR = bw;
      }
      {  // odd sub-iter: F1, Br0
        int bw = bufR + 1; if (bw == 3) bw = 0;
        VMW(8);
        dswr(smem + bw * 24576, tid, Br0);
        LB(Br0, kk + 4);
        LGK0; WGBAR;
        cmpM(acc0, acc1, smem + bufR * 24576 + frag_base, F1);
        LA(F1, kk + 3);
        bufR = bw;
      }
    }
    {  // kk = 28 (even): full body, B(31), A(30)
      int bw = bufR + 1; if (bw == 3) bw = 0;
      VMW(8);
      dswr(smem + bw * 24576, tid, Br1);
      LB(Br1, 31);
      LGK0; WGBAR;
      cmpM(acc0, acc1, smem + bufR * 24576 + frag_base, F0);
      LA(F0, 30);
      bufR = bw;
    }
    {  // kk = 29: no B-load; A(31)
      int bw = bufR + 1; if (bw == 3) bw = 0;
      VMW(8);
      dswr(smem + bw * 24576, tid, Br0);
      LGK0; WGBAR;
      cmpM(acc0, acc1, smem + bufR * 24576 + frag_base, F1);
      LA(F1, 31);
      bufR = bw;
    }
    {  // kk = 30: write B(31); outstanding B(31)6+A(30)2+A(31)2=10 -> VMW(2)
      int bw = bufR + 1; if (bw == 3) bw = 0;
      VMW(2);
      dswr(smem + bw * 24576, tid, Br1);
      LGK0; WGBAR;
      cmpM(acc0, acc1, smem + bufR * 24576 + frag_base, F0);
      bufR = bw;
    }
    {  // kk = 31: buf already barriered at kk=30
      VMW(0);
      cmpM(acc0, acc1, smem + bufR * 24576 + frag_base, F1);
    }

    // epilogue: cell1 -> h1^(t) + fc head;  cell0 -> h0^(t+1)
#pragma unroll
    for (int qq = 0; qq < 4; ++qq) {
      int b = mt2 * 64 + w * 16 + rq * 4 + qq;
      int act = p.acts[(size_t)b * T_ + t];
      float dur = p.durs[(size_t)b * T_ + t];
      float hn1v[2];
#pragma unroll
      for (int s = 0; s < 2; ++s) {
        int npb = (jt * 2 + s) * 64;
        float pre1[4];
#pragma unroll
        for (int g = 0; g < 4; ++g) pre1[g] = acc1[s][g][qq] + bzv[s][g];
        float cn1 = sigf(pre1[1]) * cv1[s][qq] + sigf(pre1[0]) * tanhf_(pre1[2]);
        float hn1 = sigf(pre1[3]) * tanhf_(cn1);
        cv1[s][qq] = cn1;
        H1n[(size_t)heb + s * 16 + b * 32] = (bf16_t)hn1;
        hn1v[s] = hn1;
        float pre0[4];
#pragma unroll
        for (int g = 0; g < 4; ++g)
          pre0[g] = acc0[s][g][qq] + chv[s][qq][g]
                  + p.E16p[(size_t)act * NG + npb + g * 16 + jj] + dur * wcv[s][g];
        float cn0 = sigf(pre0[1]) * cv0[s][qq] + sigf(pre0[0]) * tanhf_(pre0[2]);
        float hn0 = sigf(pre0[3]) * tanhf_(cn0);
        cv0[s][qq] = cn0;
        H0n[(size_t)heb + s * 16 + b * 32] = (bf16_t)hn0;
      }
      float accO = 0.f, acc16 = 0.f;
      int base = l & 48;
#pragma unroll
      for (int s = 0; s < 2; ++s) {
#pragma unroll
        for (int sc = 0; sc < 8; ++sc) {
          float hs = __shfl(hn1v[s], base | sc, 64);
          accO  += hs * (float)fcw[s][0][sc];
          acc16 += hs * (float)fw16[s][0][sc];
        }
#pragma unroll
        for (int sc = 0; sc < 8; ++sc) {
          float hs = __shfl(hn1v[s], base | (8 + sc), 64);
          accO  += hs * (float)fcw[s][1][sc];
          acc16 += hs * (float)fw16[s][1][sc];
        }
      }
      float* pb = p.preds + ((size_t)t * B_ + b) * NOUT;
      atomicAdd(pb + jj, accO);
      if (jj == 15) atomicAdd(pb + 16, acc16);
    }
    ++phase; gbar(p.slots, phase, tid, wg);
  }
}

// ---------------- launch ----------------

extern "C" void kernel_launch(void* const* d_in, const int* in_sizes, int n_in,
                              void* d_out, int out_size, void* d_ws, size_t ws_size,
                              hipStream_t stream) {
  (void)in_sizes; (void)n_in; (void)out_size; (void)ws_size;
  const float* h0   = (const float*)d_in[1];
  const float* c0   = (const float*)d_in[2];
  const float* cond = (const float*)d_in[3];
  const int*   acts = (const int*)d_in[4];
  const float* durs = (const float*)d_in[5];
  const float* emb  = (const float*)d_in[6];
  const float* ffW  = (const float*)d_in[7];
  const float* ffb  = (const float*)d_in[8];
  const float* Wih  = (const float*)d_in[9];
  const float* Whh  = (const float*)d_in[10];
  const float* bih  = (const float*)d_in[11];
  const float* bhh  = (const float*)d_in[12];
  const float* fcW  = (const float*)d_in[13];
  const float* fcb  = (const float*)d_in[14];

  char* ws = (char*)d_ws;
  size_t off = 0;
  auto alloc = [&](size_t bytes) -> char* {
    char* p0 = ws + off;
    off = (off + bytes + 255) & ~(size_t)255;
    return p0;
  };
  unsigned* slots = (unsigned*)alloc(256 * 64);
  bf16_t* PB1     = (bf16_t*)alloc((size_t)NG * H_ * 2);
  bf16_t* PB2     = (bf16_t*)alloc((size_t)NG * 2048 * 2);
  float*  CHp     = (float*)alloc((size_t)B_ * NG * 4);
  float*  E16p    = (float*)alloc((size_t)16 * NG * 4);
  float*  wcolp   = (float*)alloc((size_t)NG * 4);
  float*  biasBp  = (float*)alloc((size_t)NG * 4);
  float*  G       = (float*)alloc((size_t)33 * NG * 4);
  bf16_t* fcWp    = (bf16_t*)alloc((size_t)17 * H_ * 2);
  bf16_t* pah0i   = (bf16_t*)alloc((size_t)B_ * H_ * 2);
  bf16_t* pah0a   = (bf16_t*)alloc((size_t)B_ * H_ * 2);
  bf16_t* pah0b   = (bf16_t*)alloc((size_t)B_ * H_ * 2);
  bf16_t* pah1a   = (bf16_t*)alloc((size_t)B_ * H_ * 2);
  bf16_t* pah1b   = (bf16_t*)alloc((size_t)B_ * H_ * 2);
  float*  preds   = (float*)alloc((size_t)T_ * B_ * NOUT * 4);

  hipMemsetAsync(slots, 0, 256 * 64, stream);
  hipMemsetAsync(preds, 0, (size_t)T_ * B_ * NOUT * 4, stream);
  k_pack_wA<<<2048, 256, 0, stream>>>(Whh, PB1);
  k_pack_wB<<<4096, 256, 0, stream>>>(Wih + (size_t)NG * H_, Whh + (size_t)NG * H_, PB2);
  k_G<<<16, 256, 0, stream>>>(Wih, ffW, ffb, G);
  k_CHp<<<8192, 256, 0, stream>>>(cond, G, bih, bhh, CHp);
  k_E16<<<256, 256, 0, stream>>>(emb, Wih, E16p);
  k_misc<<<68, 256, 0, stream>>>(Wih, bih, bhh, fcW, fcWp, biasBp, wcolp);
  k_init<<<256, 256, 0, stream>>>(h0, pah0i, pah1a);

  Params prm;
  prm.acts = acts; prm.durs = durs;
  prm.PB1 = PB1; prm.PB2 = PB2;
  prm.CHp = CHp; prm.E16p = E16p; prm.wcolp = wcolp; prm.biasBp = biasBp;
  prm.fcW = fcWp;
  prm.c0in = c0;
  prm.pah0i = pah0i;
  prm.pah0a = pah0a; prm.pah0b = pah0b; prm.pah1a = pah1a; prm.pah1b = pah1b;
  prm.slots = slots; prm.preds = preds;

  lstm_main<<<dim3(256), dim3(256), 0, stream>>>(prm);
  k_out<<<(T_ * B_ + 255) / 256, 256, 0, stream>>>(preds, fcb, (float*)d_out);
}